// Round 1
// baseline (649.720 us; speedup 1.0000x reference)
//
#include <hip/hip_runtime.h>

// Problem constants
#define BB 2048
#define TT 3
#define VV 62
#define FF 5
#define HH 64

// Output layout (flat, return order): x_residual[2048*62*64], Sloss, dloss, S[2048*62*62]
#define XR_OFF 0
#define SL_OFF 8126464
#define DL_OFF 8126465
#define S_OFF  8126466

#define ALPHA_F 1e-4f
#define INV_SQRT310 0.05679618342470648f  // 1/sqrt(62*5)
#define INV_SQRT15  0.2581988897471611f   // 1/sqrt(3*5)

// Prep: transpose tw (o,c,t) -> twt (t,c,o) in workspace, zero the two loss accumulators.
__global__ void prep_kernel(const float* __restrict__ tw, float* __restrict__ twt,
                            float* __restrict__ out) {
    int i = blockIdx.x * 256 + threadIdx.x;
    if (i < 12288) {
        int t = i >> 12, r = i & 4095, c = r >> 6, o = r & 63;
        twt[i] = tw[o * 192 + c * 3 + t];
    }
    if (i < 2) out[SL_OFF + i] = 0.f;
}

__device__ __forceinline__ float rlane(float v, int l) {
    return __int_as_float(__builtin_amdgcn_readlane(__float_as_int(v), l));
}

__launch_bounds__(256, 4)
__global__ void stgcn_kernel(
    const float* __restrict__ x,     const float* __restrict__ U1,
    const float* __restrict__ U2,    const float* __restrict__ U3,
    const float* __restrict__ be,    const float* __restrict__ Ve,
    const float* __restrict__ W1,    const float* __restrict__ W2,
    const float* __restrict__ W3,    const float* __restrict__ bs,
    const float* __restrict__ Vs,    const float* __restrict__ a,
    const float* __restrict__ Theta, const float* __restrict__ twt,
    const float* __restrict__ tb,    const float* __restrict__ rw,
    const float* __restrict__ rb,    const float* __restrict__ gamma_,
    const float* __restrict__ beta_, float* __restrict__ out)
{
    // LDS budget: 930 + 3844 + 3844 + 1344 = 9962 floats = 39848 B  (<= 40960 -> 4 blocks/CU)
    __shared__ float sx[930];    // x[b] [t][v][f]           (alive whole kernel)
    __shared__ float sS[3844];   // stage C: sigmoid(s_prod+bs); stage D/F: tmpS -> S -> C1=S*At
    __shared__ float sAt[3844];  // Sm -> spatial_At -> C2=(2S^2-I)*At
    __shared__ float sU[1344];   // union scratch (stage B/C vs stage D/F)

    // stage B/C view of sU
    float* const sxT   = sU;          // 930  x_TAt [u][v][f]
    float* const sL    = sU + 930;    // 186  temporal lhs / s_lhs
    float* const sR    = sU + 1116;   // 186  temporal rhs / s_rhs
    float* const sy    = sU + 1302;   // 15
    float* const sprod = sU + 1317;   // 9
    float* const sE    = sU + 1326;   // 9
    float* const stA   = sU + 1335;   // 9
    // stage D/F view of sU (sxT/sL/sR dead by then)
    float* const sG    = sU;          // 992  G_t [v][16] (kf=15)
    float* const sDiag = sU + 992;    // 62   diag of spatial_At
    float* const scol  = sU + 1054;   // 62   1/colsum of tmpS
    float* const sred  = sU + 1116;   // 16   reductions

    const int b   = blockIdx.x;
    const int tid = threadIdx.x;
    const int o   = tid & 63;
    const int q   = tid >> 6;                              // wave id
    const int qu  = __builtin_amdgcn_readfirstlane(q);     // SGPR copy for uniform addressing
    const int nv  = (qu < 2) ? 16 : 15;                    // #valid v = qu + 4j

    // ---- stage A: loads ----
    for (int i = tid; i < 930; i += 256) sx[i] = x[b * 930 + i];
    float th[15];                                          // Theta[kf][o] in regs (was 960-float LDS)
    #pragma unroll
    for (int kf = 0; kf < 15; ++kf) th[kf] = Theta[kf * 64 + o];
    float rw5[5];
    #pragma unroll
    for (int f = 0; f < 5; ++f) rw5[f] = rw[o * 5 + f];
    const float rb_o = rb[o], tb_o = tb[o], gam = gamma_[o], bet = beta_[o];
    __syncthreads();

    // ---- stage B: temporal attention ----
    // y[t][f] = sum_v x[t][v][f]*U1[v]
    if (tid < 15) {
        int t = tid / 5, f = tid % 5;
        float s = 0.f;
        for (int v = 0; v < 62; ++v) s += sx[t * 310 + v * 5 + f] * U1[v];
        sy[tid] = s;
    }
    // rhs[v][t] = sum_f U3[f]*x[t][v][f]
    if (tid < 186) {
        int v = tid / 3, t = tid % 3;
        float s = 0.f;
        for (int f = 0; f < 5; ++f) s += U3[f] * sx[t * 310 + v * 5 + f];
        sR[v * 3 + t] = s;
    }
    __syncthreads();
    // lhs[t][u] = sum_f y[t][f]*U2[f][u]
    if (tid < 186) {
        int t = tid / 62, u = tid % 62;
        float s = 0.f;
        for (int f = 0; f < 5; ++f) s += sy[t * 5 + f] * U2[f * 62 + u];
        sL[t * 62 + u] = s;
    }
    __syncthreads();
    // prod[t][u] = sum_v lhs[t][v]*rhs[v][u]
    if (tid < 9) {
        int t = tid / 3, u = tid % 3;
        float s = 0.f;
        for (int v = 0; v < 62; ++v) s += sL[t * 62 + v] * sR[v * 3 + u];
        sprod[tid] = s;
    }
    __syncthreads();
    // E[t][u] = sum_s Ve[t][s]*sigmoid(prod[s][u]+be[s][u])
    if (tid < 9) {
        int t = tid / 3, u = tid % 3;
        float s = 0.f;
        for (int ss = 0; ss < 3; ++ss) {
            float p  = sprod[ss * 3 + u] + be[ss * 3 + u];
            float sg = 1.f / (1.f + __expf(-p));
            s += Ve[t * 3 + ss] * sg;
        }
        sE[tid] = s;
    }
    __syncthreads();
    // temporal softmax over t per u
    if (tid < 3) {
        int u = tid;
        float m = -1e30f;
        for (int t = 0; t < 3; ++t) m = fmaxf(m, sE[t * 3 + u]);
        float e0 = __expf(sE[0 * 3 + u] - m);
        float e1 = __expf(sE[1 * 3 + u] - m);
        float e2 = __expf(sE[2 * 3 + u] - m);
        float inv = 1.f / (e0 + e1 + e2);
        stA[0 * 3 + u] = e0 * inv;
        stA[1 * 3 + u] = e1 * inv;
        stA[2 * 3 + u] = e2 * inv;
    }
    __syncthreads();
    // x_TAt[u][v][f] = sum_t x[t][v][f]*At[t][u] / sqrt(310)
    for (int i = tid; i < 930; i += 256) {
        int u = i / 310, r = i % 310;
        float s = 0.f;
        for (int t = 0; t < 3; ++t) s += sx[t * 310 + r] * stA[t * 3 + u];
        sxT[i] = s * INV_SQRT310;
    }
    __syncthreads();

    // ---- stage C: spatial attention ----
    // fused: s_lhs[v][s] = sum_f (sum_t xT[t][v][f]*W1[t]) * W2[f][s]   (z2 scratch eliminated)
    //        s_rhs[t][v] = sum_f W3[f]*xT[t][v][f]
    if (tid < 186) {
        int v = tid / 3, s3 = tid - v * 3;
        float s = 0.f;
        #pragma unroll
        for (int f = 0; f < 5; ++f) {
            float z = 0.f;
            #pragma unroll
            for (int t = 0; t < 3; ++t) z += sxT[t * 310 + v * 5 + f] * W1[t];
            s += z * W2[f * 3 + s3];
        }
        sL[v * 3 + s3] = s;
        int t2 = tid / 62, v2 = tid - t2 * 62;
        float s2 = 0.f;
        #pragma unroll
        for (int f = 0; f < 5; ++f) s2 += W3[f] * sxT[t2 * 310 + v2 * 5 + f];
        sR[t2 * 62 + v2] = s2;
    }
    __syncthreads();
    // sig[u][v] = sigmoid(sum_t s_lhs[u][t]*s_rhs[t][v] + bs[u][v])  -> into sS (dead until tmpS)
    for (int i = tid; i < 3844; i += 256) {
        int u = i / 62, v = i - u * 62;
        float s = bs[i];
        for (int t = 0; t < 3; ++t) s += sL[u * 3 + t] * sR[t * 62 + v];
        sS[i] = 1.f / (1.f + __expf(-s));
    }
    __syncthreads();
    // Sm[u][v] = sum_w Vs[u][w]*sig[w][v]  — row-per-wave: u wave-uniform => Vs loads scalar-promotable
    if (o < 62) {
        for (int r = 0; r < nv; ++r) {
            int u = qu + 4 * r;
            const float* vr = Vs + u * 62;
            float s = 0.f;
            for (int w = 0; w < 62; ++w) s += vr[w] * sS[w * 62 + o];
            sAt[u * 62 + o] = s;
        }
    }
    __syncthreads();
    // spatial softmax over u (columns)
    if (tid < 62) {
        int v = tid;
        float m = -1e30f;
        for (int u = 0; u < 62; ++u) m = fmaxf(m, sAt[u * 62 + v]);
        float den = 0.f;
        for (int u = 0; u < 62; ++u) {
            float e = __expf(sAt[u * 62 + v] - m);
            sAt[u * 62 + v] = e;
            den += e;
        }
        float inv = 1.f / den;
        for (int u = 0; u < 62; ++u) sAt[u * 62 + v] *= inv;
    }

    // ---- stage D: S matrix, losses ----
    // tmpS[i][j] = exp(relu(sum_f |xm[i][f]-xm[j][f]|*a[f])), xm = x[:,1]  (overwrites sig in sS)
    for (int idx = tid; idx < 3844; idx += 256) {
        int i = idx / 62, j = idx - i * 62;
        float s = 0.f;
        #pragma unroll
        for (int f = 0; f < 5; ++f)
            s += fabsf(sx[310 + i * 5 + f] - sx[310 + j * 5 + f]) * a[f];
        sS[idx] = __expf(fmaxf(s, 0.f));
    }
    __syncthreads();
    if (tid < 62) {
        int j = tid;
        float s = 0.f;
        for (int i = 0; i < 62; ++i) s += sS[i * 62 + j];
        scol[j] = 1.f / s;
    }
    // dloss partial: sum_{j,f} d2 = sum_f (2*62*sum(xm^2) - 2*(sum xm)^2)
    if (tid < 5) {
        float su = 0.f, sq = 0.f;
        for (int v = 0; v < 62; ++v) {
            float xv = sx[310 + v * 5 + tid];
            su += xv; sq += xv * xv;
        }
        sred[8 + tid] = 124.f * sq - 2.f * su * su;
    }
    __syncthreads();
    // normalize S, write out, Sloss partial; fuse C1/C2 transform
    float slp = 0.f;
    for (int idx = tid; idx < 3844; idx += 256) {
        int i = idx / 62, j = idx - i * 62;
        float sv = sS[idx] * scol[j];
        out[S_OFF + (size_t)b * 3844 + idx] = sv;
        slp += sv * sv;
        float A = sAt[idx];
        if (i == j) sDiag[i] = A;
        sS[idx] = sv * A;                               // C1 = S*At
        float c2 = 2.f * sv * sv; if (i == j) c2 -= 1.f;
        sAt[idx] = c2 * A;                              // C2 = (2S^2 - I)*At
    }
    // Sloss reduce
    for (int m = 32; m > 0; m >>= 1) slp += __shfl_down(slp, m, 64);
    if ((tid & 63) == 0) sred[q] = slp;
    __syncthreads();
    if (tid == 0) {
        atomicAdd(out + SL_OFF, (sred[0] + sred[1] + sred[2] + sred[3]) * (ALPHA_F / 2048.f));
        float dl = sred[8] + sred[9] + sred[10] + sred[11] + sred[12];
        atomicAdd(out + DL_OFF, dl * ALPHA_F);
    }

    // ---- stage F: spatial GCN + temporal conv, gcn tile in regs + readlane (sP/sTh eliminated) ----
    float acc[16];
    #pragma unroll
    for (int j = 0; j < 16; ++j) acc[j] = 0.f;

    for (int t = 0; t < 3; ++t) {
        __syncthreads();
        // step1: G_t[v][kf]  (kf = k*5+f, k in {0,1,2})
        for (int i = tid; i < 310; i += 256) {
            int v = i / 5, f = i - v * 5;
            float g0 = sDiag[v] * sx[t * 310 + i];
            float g1 = 0.f, g2 = 0.f;
            for (int u = 0; u < 62; ++u) {
                float xa = sx[t * 310 + u * 5 + f];
                g1 -= sS[u * 62 + v] * xa;   // cheb1 = -S
                g2 += sAt[u * 62 + v] * xa;  // cheb2 = 2S^2 - I
            }
            sG[v * 16 + f]      = g0;
            sG[v * 16 + 5 + f]  = g1;
            sG[v * 16 + 10 + f] = g2;
        }
        __syncthreads();
        // step2: gval[j] = relu(sum_kf G[v][kf]*Theta[kf][o])  — lane o holds gcn_t[v][o]
        float gval[16];
        #pragma unroll
        for (int j = 0; j < 16; ++j) {
            float s = 0.f;
            if (j < nv) {
                int v = qu + 4 * j;
                #pragma unroll
                for (int kf = 0; kf < 15; ++kf) s += sG[v * 16 + kf] * th[kf];
            }
            gval[j] = fmaxf(s, 0.f);
        }
        // step3: tc[o][v] += sum_c gcn_t[v][c]*tw[o][c][t]  — readlane broadcast, no LDS
        const float* twtp = twt + t * 4096;
        for (int c = 0; c < 64; ++c) {
            float w = twtp[c * 64 + o];   // coalesced, L1-hot
            #pragma unroll
            for (int j = 0; j < 16; ++j) {
                acc[j] += rlane(gval[j], c) * w;   // gval[j]=0 for j>=nv
            }
        }
    }

    // ---- epilogue: res + tc, relu, LayerNorm over o (64 lanes of wave) ----
    #pragma unroll
    for (int j = 0; j < 16; ++j) {
        if (j < nv) {
            int v = qu + 4 * j;
            float r = rb_o;
            #pragma unroll
            for (int f = 0; f < 5; ++f) r += sx[v * 5 + f] * rw5[f];  // x[:,0]
            float z = r + (acc[j] + tb_o) * INV_SQRT15;
            z = fmaxf(z, 0.f);
            float s1 = z, s2 = z * z;
            #pragma unroll
            for (int m = 1; m < 64; m <<= 1) {
                s1 += __shfl_xor(s1, m, 64);
                s2 += __shfl_xor(s2, m, 64);
            }
            float mean = s1 * 0.015625f;
            float var  = s2 * 0.015625f - mean * mean;
            float ov   = (z - mean) * rsqrtf(var + 1e-5f) * gam + bet;
            out[XR_OFF + (size_t)b * 3968 + v * 64 + o] = ov;
        }
    }
}

extern "C" void kernel_launch(void* const* d_in, const int* in_sizes, int n_in,
                              void* d_out, int out_size, void* d_ws, size_t ws_size,
                              hipStream_t stream) {
    const float* x   = (const float*)d_in[0];
    const float* U1  = (const float*)d_in[1];
    const float* U2  = (const float*)d_in[2];
    const float* U3  = (const float*)d_in[3];
    const float* be  = (const float*)d_in[4];
    const float* Ve  = (const float*)d_in[5];
    const float* W1  = (const float*)d_in[6];
    const float* W2  = (const float*)d_in[7];
    const float* W3  = (const float*)d_in[8];
    const float* bs  = (const float*)d_in[9];
    const float* Vs  = (const float*)d_in[10];
    const float* a   = (const float*)d_in[11];
    const float* Th  = (const float*)d_in[12];
    const float* tw  = (const float*)d_in[13];
    const float* tb  = (const float*)d_in[14];
    const float* rw  = (const float*)d_in[15];
    const float* rb  = (const float*)d_in[16];
    const float* gm  = (const float*)d_in[17];
    const float* bt  = (const float*)d_in[18];
    float* out = (float*)d_out;
    float* twt = (float*)d_ws;  // 12288 floats

    prep_kernel<<<48, 256, 0, stream>>>(tw, twt, out);
    stgcn_kernel<<<2048, 256, 0, stream>>>(x, U1, U2, U3, be, Ve, W1, W2, W3,
                                           bs, Vs, a, Th, twt, tb, rw, rb, gm, bt, out);
}

// Round 2
// 485.441 us; speedup vs baseline: 1.3384x; 1.3384x over previous
//
#include <hip/hip_runtime.h>

// Problem constants
#define BB 2048
#define TT 3
#define VV 62
#define FF 5
#define HH 64

// Output layout (flat, return order): x_residual[2048*62*64], Sloss, dloss, S[2048*62*62]
#define XR_OFF 0
#define SL_OFF 8126464
#define DL_OFF 8126465
#define S_OFF  8126466

#define ALPHA_F 1e-4f
#define INV_SQRT310 0.05679618342470648f  // 1/sqrt(62*5)
#define INV_SQRT15  0.2581988897471611f   // 1/sqrt(3*5)

// Prep: transpose tw (o,c,t) -> twt (t,c,o) in workspace, zero the two loss accumulators.
__global__ void prep_kernel(const float* __restrict__ tw, float* __restrict__ twt,
                            float* __restrict__ out) {
    int i = blockIdx.x * 256 + threadIdx.x;
    if (i < 12288) {
        int t = i >> 12, r = i & 4095, c = r >> 6, o = r & 63;
        twt[i] = tw[o * 192 + c * 3 + t];
    }
    if (i < 2) out[SL_OFF + i] = 0.f;
}

__device__ __forceinline__ float rlane(float v, int l) {
    return __int_as_float(__builtin_amdgcn_readlane(__float_as_int(v), l));
}

__launch_bounds__(256)
__attribute__((amdgpu_waves_per_eu(4, 4)))   // pin RA target: exactly 4 waves/EU -> 128 VGPR budget, no spill-to-64
__global__ void stgcn_kernel(
    const float* __restrict__ x,     const float* __restrict__ U1,
    const float* __restrict__ U2,    const float* __restrict__ U3,
    const float* __restrict__ be,    const float* __restrict__ Ve,
    const float* __restrict__ W1,    const float* __restrict__ W2,
    const float* __restrict__ W3,    const float* __restrict__ bs,
    const float* __restrict__ Vs,    const float* __restrict__ a,
    const float* __restrict__ Theta, const float* __restrict__ twt,
    const float* __restrict__ tb,    const float* __restrict__ rw,
    const float* __restrict__ rb,    const float* __restrict__ gamma_,
    const float* __restrict__ beta_, float* __restrict__ out)
{
    // LDS budget: 930 + 3844 + 3844 + 1344 = 9962 floats = 39848 B  (<= 40960 -> 4 blocks/CU)
    __shared__ float sx[930];    // x[b] [t][v][f]           (alive whole kernel)
    __shared__ float sS[3844];   // stage C: sigmoid(s_prod+bs); stage D/F: tmpS -> S -> C1=S*At
    __shared__ float sAt[3844];  // Sm -> spatial_At -> C2=(2S^2-I)*At
    __shared__ float sU[1344];   // union scratch (stage B/C vs stage D/F)

    // stage B/C view of sU
    float* const sxT   = sU;          // 930  x_TAt [u][v][f]
    float* const sL    = sU + 930;    // 186  temporal lhs / s_lhs
    float* const sR    = sU + 1116;   // 186  temporal rhs / s_rhs
    float* const sy    = sU + 1302;   // 15
    float* const sprod = sU + 1317;   // 9
    float* const sE    = sU + 1326;   // 9
    float* const stA   = sU + 1335;   // 9
    // stage D/F view of sU (sxT/sL/sR dead by then)
    float* const sG    = sU;          // 992  G_t [v][16] (kf=15)
    float* const sDiag = sU + 992;    // 62   diag of spatial_At
    float* const scol  = sU + 1054;   // 62   1/colsum of tmpS
    float* const sred  = sU + 1116;   // 16   reductions

    const int b   = blockIdx.x;
    const int tid = threadIdx.x;
    const int o   = tid & 63;
    const int q   = tid >> 6;                              // wave id
    const int qu  = __builtin_amdgcn_readfirstlane(q);     // SGPR copy for uniform addressing
    const int nv  = (qu < 2) ? 16 : 15;                    // #valid v = qu + 4j

    // ---- stage A: loads ----
    for (int i = tid; i < 930; i += 256) sx[i] = x[b * 930 + i];
    __syncthreads();

    // ---- stage B: temporal attention ----
    // y[t][f] = sum_v x[t][v][f]*U1[v]
    if (tid < 15) {
        int t = tid / 5, f = tid % 5;
        float s = 0.f;
        for (int v = 0; v < 62; ++v) s += sx[t * 310 + v * 5 + f] * U1[v];
        sy[tid] = s;
    }
    // rhs[v][t] = sum_f U3[f]*x[t][v][f]
    if (tid < 186) {
        int v = tid / 3, t = tid % 3;
        float s = 0.f;
        for (int f = 0; f < 5; ++f) s += U3[f] * sx[t * 310 + v * 5 + f];
        sR[v * 3 + t] = s;
    }
    __syncthreads();
    // lhs[t][u] = sum_f y[t][f]*U2[f][u]
    if (tid < 186) {
        int t = tid / 62, u = tid % 62;
        float s = 0.f;
        for (int f = 0; f < 5; ++f) s += sy[t * 5 + f] * U2[f * 62 + u];
        sL[t * 62 + u] = s;
    }
    __syncthreads();
    // prod[t][u] = sum_v lhs[t][v]*rhs[v][u]
    if (tid < 9) {
        int t = tid / 3, u = tid % 3;
        float s = 0.f;
        for (int v = 0; v < 62; ++v) s += sL[t * 62 + v] * sR[v * 3 + u];
        sprod[tid] = s;
    }
    __syncthreads();
    // E[t][u] = sum_s Ve[t][s]*sigmoid(prod[s][u]+be[s][u])
    if (tid < 9) {
        int t = tid / 3, u = tid % 3;
        float s = 0.f;
        for (int ss = 0; ss < 3; ++ss) {
            float p  = sprod[ss * 3 + u] + be[ss * 3 + u];
            float sg = 1.f / (1.f + __expf(-p));
            s += Ve[t * 3 + ss] * sg;
        }
        sE[tid] = s;
    }
    __syncthreads();
    // temporal softmax over t per u
    if (tid < 3) {
        int u = tid;
        float m = -1e30f;
        for (int t = 0; t < 3; ++t) m = fmaxf(m, sE[t * 3 + u]);
        float e0 = __expf(sE[0 * 3 + u] - m);
        float e1 = __expf(sE[1 * 3 + u] - m);
        float e2 = __expf(sE[2 * 3 + u] - m);
        float inv = 1.f / (e0 + e1 + e2);
        stA[0 * 3 + u] = e0 * inv;
        stA[1 * 3 + u] = e1 * inv;
        stA[2 * 3 + u] = e2 * inv;
    }
    __syncthreads();
    // x_TAt[u][v][f] = sum_t x[t][v][f]*At[t][u] / sqrt(310)
    for (int i = tid; i < 930; i += 256) {
        int u = i / 310, r = i % 310;
        float s = 0.f;
        for (int t = 0; t < 3; ++t) s += sx[t * 310 + r] * stA[t * 3 + u];
        sxT[i] = s * INV_SQRT310;
    }
    __syncthreads();

    // ---- stage C: spatial attention ----
    // fused: s_lhs[v][s] = sum_f (sum_t xT[t][v][f]*W1[t]) * W2[f][s]   (z2 scratch eliminated)
    //        s_rhs[t][v] = sum_f W3[f]*xT[t][v][f]
    if (tid < 186) {
        int v = tid / 3, s3 = tid - v * 3;
        float s = 0.f;
        #pragma unroll
        for (int f = 0; f < 5; ++f) {
            float z = 0.f;
            #pragma unroll
            for (int t = 0; t < 3; ++t) z += sxT[t * 310 + v * 5 + f] * W1[t];
            s += z * W2[f * 3 + s3];
        }
        sL[v * 3 + s3] = s;
        int t2 = tid / 62, v2 = tid - t2 * 62;
        float s2 = 0.f;
        #pragma unroll
        for (int f = 0; f < 5; ++f) s2 += W3[f] * sxT[t2 * 310 + v2 * 5 + f];
        sR[t2 * 62 + v2] = s2;
    }
    __syncthreads();
    // sig[u][v] = sigmoid(sum_t s_lhs[u][t]*s_rhs[t][v] + bs[u][v])  -> into sS (dead until tmpS)
    for (int i = tid; i < 3844; i += 256) {
        int u = i / 62, v = i - u * 62;
        float s = bs[i];
        for (int t = 0; t < 3; ++t) s += sL[u * 3 + t] * sR[t * 62 + v];
        sS[i] = 1.f / (1.f + __expf(-s));
    }
    __syncthreads();
    // Sm[u][v] = sum_w Vs[u][w]*sig[w][v]  — row-per-wave: u wave-uniform => Vs loads scalar-promotable
    if (o < 62) {
        for (int r = 0; r < nv; ++r) {
            int u = qu + 4 * r;
            const float* vr = Vs + u * 62;
            float s = 0.f;
            for (int w = 0; w < 62; ++w) s += vr[w] * sS[w * 62 + o];
            sAt[u * 62 + o] = s;
        }
    }
    __syncthreads();
    // spatial softmax over u (columns)
    if (tid < 62) {
        int v = tid;
        float m = -1e30f;
        for (int u = 0; u < 62; ++u) m = fmaxf(m, sAt[u * 62 + v]);
        float den = 0.f;
        for (int u = 0; u < 62; ++u) {
            float e = __expf(sAt[u * 62 + v] - m);
            sAt[u * 62 + v] = e;
            den += e;
        }
        float inv = 1.f / den;
        for (int u = 0; u < 62; ++u) sAt[u * 62 + v] *= inv;
    }

    // ---- stage D: S matrix, losses ----
    // tmpS[i][j] = exp(relu(sum_f |xm[i][f]-xm[j][f]|*a[f])), xm = x[:,1]  (overwrites sig in sS)
    for (int idx = tid; idx < 3844; idx += 256) {
        int i = idx / 62, j = idx - i * 62;
        float s = 0.f;
        #pragma unroll
        for (int f = 0; f < 5; ++f)
            s += fabsf(sx[310 + i * 5 + f] - sx[310 + j * 5 + f]) * a[f];
        sS[idx] = __expf(fmaxf(s, 0.f));
    }
    __syncthreads();
    if (tid < 62) {
        int j = tid;
        float s = 0.f;
        for (int i = 0; i < 62; ++i) s += sS[i * 62 + j];
        scol[j] = 1.f / s;
    }
    // dloss partial: sum_{j,f} d2 = sum_f (2*62*sum(xm^2) - 2*(sum xm)^2)
    if (tid < 5) {
        float su = 0.f, sq = 0.f;
        for (int v = 0; v < 62; ++v) {
            float xv = sx[310 + v * 5 + tid];
            su += xv; sq += xv * xv;
        }
        sred[8 + tid] = 124.f * sq - 2.f * su * su;
    }
    __syncthreads();
    // normalize S, write out, Sloss partial; fuse C1/C2 transform
    float slp = 0.f;
    for (int idx = tid; idx < 3844; idx += 256) {
        int i = idx / 62, j = idx - i * 62;
        float sv = sS[idx] * scol[j];
        out[S_OFF + (size_t)b * 3844 + idx] = sv;
        slp += sv * sv;
        float A = sAt[idx];
        if (i == j) sDiag[i] = A;
        sS[idx] = sv * A;                               // C1 = S*At
        float c2 = 2.f * sv * sv; if (i == j) c2 -= 1.f;
        sAt[idx] = c2 * A;                              // C2 = (2S^2 - I)*At
    }
    // Sloss reduce
    for (int m = 32; m > 0; m >>= 1) slp += __shfl_down(slp, m, 64);
    if ((tid & 63) == 0) sred[q] = slp;
    __syncthreads();
    if (tid == 0) {
        atomicAdd(out + SL_OFF, (sred[0] + sred[1] + sred[2] + sred[3]) * (ALPHA_F / 2048.f));
        float dl = sred[8] + sred[9] + sred[10] + sred[11] + sred[12];
        atomicAdd(out + DL_OFF, dl * ALPHA_F);
    }

    // ---- stage F: spatial GCN + temporal conv, gcn tile in regs + readlane (no LDS round-trip) ----
    float th[15];                                          // Theta[kf][o] in regs (late load: short live range)
    #pragma unroll
    for (int kf = 0; kf < 15; ++kf) th[kf] = Theta[kf * 64 + o];

    float acc[16];
    #pragma unroll
    for (int j = 0; j < 16; ++j) acc[j] = 0.f;

    for (int t = 0; t < 3; ++t) {
        __syncthreads();
        // step1: G_t[v][kf]  (kf = k*5+f, k in {0,1,2})
        for (int i = tid; i < 310; i += 256) {
            int v = i / 5, f = i - v * 5;
            float g0 = sDiag[v] * sx[t * 310 + i];
            float g1 = 0.f, g2 = 0.f;
            for (int u = 0; u < 62; ++u) {
                float xa = sx[t * 310 + u * 5 + f];
                g1 -= sS[u * 62 + v] * xa;   // cheb1 = -S
                g2 += sAt[u * 62 + v] * xa;  // cheb2 = 2S^2 - I
            }
            sG[v * 16 + f]      = g0;
            sG[v * 16 + 5 + f]  = g1;
            sG[v * 16 + 10 + f] = g2;
        }
        __syncthreads();
        // steps 2+3 in two j-halves of 8 to halve peak VGPR pressure:
        //   gval[jj] = relu(sum_kf G[v][kf]*Theta[kf][o]); then
        //   acc[j]  += gcn_t[v][c]*tw[o][c][t] via readlane broadcast (no LDS)
        const float* twtp = twt + t * 4096;
        #pragma unroll
        for (int half = 0; half < 2; ++half) {
            float gval[8];
            #pragma unroll
            for (int jj = 0; jj < 8; ++jj) {
                int j = half * 8 + jj;
                float s = 0.f;
                if (j < nv) {
                    int v = qu + 4 * j;
                    #pragma unroll
                    for (int kf = 0; kf < 15; ++kf) s += sG[v * 16 + kf] * th[kf];
                }
                gval[jj] = fmaxf(s, 0.f);
            }
            for (int c = 0; c < 64; ++c) {
                float w = twtp[c * 64 + o];   // coalesced, L1-hot
                #pragma unroll
                for (int jj = 0; jj < 8; ++jj)
                    acc[half * 8 + jj] += rlane(gval[jj], c) * w;   // gval=0 for j>=nv
            }
        }
    }

    // ---- epilogue: res + tc, relu, LayerNorm over o (64 lanes of wave) ----
    float rw5[5];
    #pragma unroll
    for (int f = 0; f < 5; ++f) rw5[f] = rw[o * 5 + f];
    const float rb_o = rb[o], tb_o = tb[o], gam = gamma_[o], bet = beta_[o];

    #pragma unroll
    for (int j = 0; j < 16; ++j) {
        if (j < nv) {
            int v = qu + 4 * j;
            float r = rb_o;
            #pragma unroll
            for (int f = 0; f < 5; ++f) r += sx[v * 5 + f] * rw5[f];  // x[:,0]
            float z = r + (acc[j] + tb_o) * INV_SQRT15;
            z = fmaxf(z, 0.f);
            float s1 = z, s2 = z * z;
            #pragma unroll
            for (int m = 1; m < 64; m <<= 1) {
                s1 += __shfl_xor(s1, m, 64);
                s2 += __shfl_xor(s2, m, 64);
            }
            float mean = s1 * 0.015625f;
            float var  = s2 * 0.015625f - mean * mean;
            float ov   = (z - mean) * rsqrtf(var + 1e-5f) * gam + bet;
            out[XR_OFF + (size_t)b * 3968 + v * 64 + o] = ov;
        }
    }
}

extern "C" void kernel_launch(void* const* d_in, const int* in_sizes, int n_in,
                              void* d_out, int out_size, void* d_ws, size_t ws_size,
                              hipStream_t stream) {
    const float* x   = (const float*)d_in[0];
    const float* U1  = (const float*)d_in[1];
    const float* U2  = (const float*)d_in[2];
    const float* U3  = (const float*)d_in[3];
    const float* be  = (const float*)d_in[4];
    const float* Ve  = (const float*)d_in[5];
    const float* W1  = (const float*)d_in[6];
    const float* W2  = (const float*)d_in[7];
    const float* W3  = (const float*)d_in[8];
    const float* bs  = (const float*)d_in[9];
    const float* Vs  = (const float*)d_in[10];
    const float* a   = (const float*)d_in[11];
    const float* Th  = (const float*)d_in[12];
    const float* tw  = (const float*)d_in[13];
    const float* tb  = (const float*)d_in[14];
    const float* rw  = (const float*)d_in[15];
    const float* rb  = (const float*)d_in[16];
    const float* gm  = (const float*)d_in[17];
    const float* bt  = (const float*)d_in[18];
    float* out = (float*)d_out;
    float* twt = (float*)d_ws;  // 12288 floats

    prep_kernel<<<48, 256, 0, stream>>>(tw, twt, out);
    stgcn_kernel<<<2048, 256, 0, stream>>>(x, U1, U2, U3, be, Ve, W1, W2, W3,
                                           bs, Vs, a, Th, twt, tb, rw, rb, gm, bt, out);
}

// Round 3
// 437.808 us; speedup vs baseline: 1.4840x; 1.1088x over previous
//
#include <hip/hip_runtime.h>

// Problem constants
#define BB 2048
#define TT 3
#define VV 62
#define FF 5
#define HH 64

// Output layout (flat, return order): x_residual[2048*62*64], Sloss, dloss, S[2048*62*62]
#define XR_OFF 0
#define SL_OFF 8126464
#define DL_OFF 8126465
#define S_OFF  8126466

#define ALPHA_F 1e-4f
#define INV_SQRT310 0.05679618342470648f  // 1/sqrt(62*5)
#define INV_SQRT15  0.2581988897471611f   // 1/sqrt(3*5)

// Prep: transpose tw (o,c,t) -> twt (t,c,o) in workspace, zero the two loss accumulators.
__global__ void prep_kernel(const float* __restrict__ tw, float* __restrict__ twt,
                            float* __restrict__ out) {
    int i = blockIdx.x * 256 + threadIdx.x;
    if (i < 12288) {
        int t = i >> 12, r = i & 4095, c = r >> 6, o = r & 63;
        twt[i] = tw[o * 192 + c * 3 + t];
    }
    if (i < 2) out[SL_OFF + i] = 0.f;
}

__device__ __forceinline__ float rlane(float v, int l) {
    return __int_as_float(__builtin_amdgcn_readlane(__float_as_int(v), l));
}

__launch_bounds__(256, 2)   // known-good RA contract from round 0 (92 VGPR, no spill)
__global__ void stgcn_kernel(
    const float* __restrict__ x,     const float* __restrict__ U1,
    const float* __restrict__ U2,    const float* __restrict__ U3,
    const float* __restrict__ be,    const float* __restrict__ Ve,
    const float* __restrict__ W1,    const float* __restrict__ W2,
    const float* __restrict__ W3,    const float* __restrict__ bs,
    const float* __restrict__ Vs,    const float* __restrict__ a,
    const float* __restrict__ Theta, const float* __restrict__ twt,
    const float* __restrict__ tb,    const float* __restrict__ rw,
    const float* __restrict__ rb,    const float* __restrict__ gamma_,
    const float* __restrict__ beta_, float* __restrict__ out)
{
    // LDS: 930 + 3844 + 3844 + 1132 = 9750 floats = 39000 B  (<= 40960 -> 4 blocks/CU)
    __shared__ float sx[930];    // x[b] [t][v][f]           (alive whole kernel)
    __shared__ float sS[3844];   // stage C: sigmoid(s_prod+bs); stage D/F: tmpS -> S -> C1=S*At
    __shared__ float sAt[3844];  // Sm -> spatial_At -> C2=(2S^2-I)*At
    __shared__ float sU[1132];   // union scratch (stage B/C vs stage D/F)

    // stage B/C view of sU  (x_TAt never materialized: factored via w1t / R0)
    float* const sL    = sU;          // 186  temporal lhs [t][u62] -> s_lhs [v][3]
    float* const sR    = sU + 186;    // 186  temporal rhs [v][t3]
    float* const sR0   = sU + 372;    // 186  R0[t][v] = sum_f W3[f]*x[t][v][f]
    float* const sRr   = sU + 558;    // 186  s_rhs [t][v62]
    float* const sy    = sU + 744;    // 15
    float* const sprod = sU + 759;    // 9
    float* const sE    = sU + 768;    // 9
    float* const stA   = sU + 777;    // 9
    // stage D/F view of sU (all B/C buffers dead by then)
    float* const sG    = sU;          // 992  G_t [v][16] (kf=15)
    float* const sDiag = sU + 992;    // 62   diag of spatial_At
    float* const scol  = sU + 1054;   // 62   1/colsum of tmpS
    float* const sred  = sU + 1116;   // 16   reductions

    const int b   = blockIdx.x;
    const int tid = threadIdx.x;
    const int o   = tid & 63;
    const int q   = tid >> 6;                              // wave id
    const int qu  = __builtin_amdgcn_readfirstlane(q);     // SGPR copy for uniform addressing
    const int nv  = (qu < 2) ? 16 : 15;                    // #valid v = qu + 4j

    // ---- stage A: loads ----
    for (int i = tid; i < 930; i += 256) sx[i] = x[b * 930 + i];
    __syncthreads();

    // ---- stage B: temporal attention ----
    // y[t][f] = sum_v x[t][v][f]*U1[v]
    if (tid < 15) {
        int t = tid / 5, f = tid % 5;
        float s = 0.f;
        for (int v = 0; v < 62; ++v) s += sx[t * 310 + v * 5 + f] * U1[v];
        sy[tid] = s;
    }
    // rhs[v][t] = sum_f U3[f]*x[t][v][f]; also R0[t][v] = sum_f W3[f]*x[t][v][f] (for stage C)
    if (tid < 186) {
        int v = tid / 3, t = tid % 3;
        float s = 0.f, s0 = 0.f;
        #pragma unroll
        for (int f = 0; f < 5; ++f) {
            float xv = sx[t * 310 + v * 5 + f];
            s  += U3[f] * xv;
            s0 += W3[f] * xv;
        }
        sR[v * 3 + t]  = s;
        sR0[t * 62 + v] = s0;
    }
    __syncthreads();
    // lhs[t][u] = sum_f y[t][f]*U2[f][u]
    if (tid < 186) {
        int t = tid / 62, u = tid % 62;
        float s = 0.f;
        for (int f = 0; f < 5; ++f) s += sy[t * 5 + f] * U2[f * 62 + u];
        sL[t * 62 + u] = s;
    }
    __syncthreads();
    // prod[t][u] = sum_v lhs[t][v]*rhs[v][u]
    if (tid < 9) {
        int t = tid / 3, u = tid % 3;
        float s = 0.f;
        for (int v = 0; v < 62; ++v) s += sL[t * 62 + v] * sR[v * 3 + u];
        sprod[tid] = s;
    }
    __syncthreads();
    // E[t][u] = sum_s Ve[t][s]*sigmoid(prod[s][u]+be[s][u])
    if (tid < 9) {
        int t = tid / 3, u = tid % 3;
        float s = 0.f;
        for (int ss = 0; ss < 3; ++ss) {
            float p  = sprod[ss * 3 + u] + be[ss * 3 + u];
            float sg = 1.f / (1.f + __expf(-p));
            s += Ve[t * 3 + ss] * sg;
        }
        sE[tid] = s;
    }
    __syncthreads();
    // temporal softmax over t per u
    if (tid < 3) {
        int u = tid;
        float m = -1e30f;
        for (int t = 0; t < 3; ++t) m = fmaxf(m, sE[t * 3 + u]);
        float e0 = __expf(sE[0 * 3 + u] - m);
        float e1 = __expf(sE[1 * 3 + u] - m);
        float e2 = __expf(sE[2 * 3 + u] - m);
        float inv = 1.f / (e0 + e1 + e2);
        stA[0 * 3 + u] = e0 * inv;
        stA[1 * 3 + u] = e1 * inv;
        stA[2 * 3 + u] = e2 * inv;
    }
    __syncthreads();

    // ---- stage C: spatial attention (x_TAt factored out) ----
    // s_lhs[v][s] = INV * sum_f (sum_t x[t][v][f]*w1t[t]) * W2[f][s],  w1t[t]=sum_u W1[u]*At[t][u]
    // s_rhs[u][v] = INV * sum_t At[t][u] * R0[t][v]
    if (tid < 186) {
        float w1t[3];
        #pragma unroll
        for (int t = 0; t < 3; ++t) {
            float s = 0.f;
            #pragma unroll
            for (int u = 0; u < 3; ++u) s += W1[u] * stA[t * 3 + u];
            w1t[t] = s;
        }
        int v = tid / 3, s3 = tid - v * 3;
        float s = 0.f;
        #pragma unroll
        for (int f = 0; f < 5; ++f) {
            float z = 0.f;
            #pragma unroll
            for (int t = 0; t < 3; ++t) z += sx[t * 310 + v * 5 + f] * w1t[t];
            s += z * W2[f * 3 + s3];
        }
        sL[v * 3 + s3] = s * INV_SQRT310;
        int u2 = tid / 62, v2 = tid - u2 * 62;
        float s2 = 0.f;
        #pragma unroll
        for (int t = 0; t < 3; ++t) s2 += stA[t * 3 + u2] * sR0[t * 62 + v2];
        sRr[u2 * 62 + v2] = s2 * INV_SQRT310;
    }
    __syncthreads();
    // sig[u][v] = sigmoid(sum_t s_lhs[u][t]*s_rhs[t][v] + bs[u][v])  -> into sS (dead until tmpS)
    for (int i = tid; i < 3844; i += 256) {
        int u = i / 62, v = i - u * 62;
        float s = bs[i];
        for (int t = 0; t < 3; ++t) s += sL[u * 3 + t] * sRr[t * 62 + v];
        sS[i] = 1.f / (1.f + __expf(-s));
    }
    __syncthreads();
    // Sm[u][v] = sum_w Vs[u][w]*sig[w][v]  — row-per-wave: u wave-uniform => Vs loads scalar-promotable
    if (o < 62) {
        for (int r = 0; r < nv; ++r) {
            int u = qu + 4 * r;
            const float* vr = Vs + u * 62;
            float s = 0.f;
            for (int w = 0; w < 62; ++w) s += vr[w] * sS[w * 62 + o];
            sAt[u * 62 + o] = s;
        }
    }
    __syncthreads();
    // spatial softmax over u (columns)
    if (tid < 62) {
        int v = tid;
        float m = -1e30f;
        for (int u = 0; u < 62; ++u) m = fmaxf(m, sAt[u * 62 + v]);
        float den = 0.f;
        for (int u = 0; u < 62; ++u) {
            float e = __expf(sAt[u * 62 + v] - m);
            sAt[u * 62 + v] = e;
            den += e;
        }
        float inv = 1.f / den;
        for (int u = 0; u < 62; ++u) sAt[u * 62 + v] *= inv;
    }

    // ---- stage D: S matrix, losses ----
    // tmpS[i][j] = exp(relu(sum_f |xm[i][f]-xm[j][f]|*a[f])), xm = x[:,1]  (overwrites sig in sS)
    for (int idx = tid; idx < 3844; idx += 256) {
        int i = idx / 62, j = idx - i * 62;
        float s = 0.f;
        #pragma unroll
        for (int f = 0; f < 5; ++f)
            s += fabsf(sx[310 + i * 5 + f] - sx[310 + j * 5 + f]) * a[f];
        sS[idx] = __expf(fmaxf(s, 0.f));
    }
    __syncthreads();
    if (tid < 62) {
        int j = tid;
        float s = 0.f;
        for (int i = 0; i < 62; ++i) s += sS[i * 62 + j];
        scol[j] = 1.f / s;
    }
    // dloss partial: sum_{j,f} d2 = sum_f (2*62*sum(xm^2) - 2*(sum xm)^2)
    if (tid < 5) {
        float su = 0.f, sq = 0.f;
        for (int v = 0; v < 62; ++v) {
            float xv = sx[310 + v * 5 + tid];
            su += xv; sq += xv * xv;
        }
        sred[8 + tid] = 124.f * sq - 2.f * su * su;
    }
    __syncthreads();
    // normalize S, write out, Sloss partial; fuse C1/C2 transform
    float slp = 0.f;
    for (int idx = tid; idx < 3844; idx += 256) {
        int i = idx / 62, j = idx - i * 62;
        float sv = sS[idx] * scol[j];
        out[S_OFF + (size_t)b * 3844 + idx] = sv;
        slp += sv * sv;
        float A = sAt[idx];
        if (i == j) sDiag[i] = A;
        sS[idx] = sv * A;                               // C1 = S*At
        float c2 = 2.f * sv * sv; if (i == j) c2 -= 1.f;
        sAt[idx] = c2 * A;                              // C2 = (2S^2 - I)*At
    }
    // Sloss reduce
    for (int m = 32; m > 0; m >>= 1) slp += __shfl_down(slp, m, 64);
    if ((tid & 63) == 0) sred[q] = slp;
    __syncthreads();
    if (tid == 0) {
        atomicAdd(out + SL_OFF, (sred[0] + sred[1] + sred[2] + sred[3]) * (ALPHA_F / 2048.f));
        float dl = sred[8] + sred[9] + sred[10] + sred[11] + sred[12];
        atomicAdd(out + DL_OFF, dl * ALPHA_F);
    }

    // ---- stage F: spatial GCN + temporal conv, gcn tile in regs + readlane ----
    float th[15];                                          // Theta[kf][o] in regs
    #pragma unroll
    for (int kf = 0; kf < 15; ++kf) th[kf] = Theta[kf * 64 + o];

    float acc[16];
    #pragma unroll
    for (int j = 0; j < 16; ++j) acc[j] = 0.f;

    for (int t = 0; t < 3; ++t) {
        __syncthreads();
        // step1: G_t[v][kf]  (kf = k*5+f, k in {0,1,2})
        for (int i = tid; i < 310; i += 256) {
            int v = i / 5, f = i - v * 5;
            float g0 = sDiag[v] * sx[t * 310 + i];
            float g1 = 0.f, g2 = 0.f;
            for (int u = 0; u < 62; ++u) {
                float xa = sx[t * 310 + u * 5 + f];
                g1 -= sS[u * 62 + v] * xa;   // cheb1 = -S
                g2 += sAt[u * 62 + v] * xa;  // cheb2 = 2S^2 - I
            }
            sG[v * 16 + f]      = g0;
            sG[v * 16 + 5 + f]  = g1;
            sG[v * 16 + 10 + f] = g2;
        }
        __syncthreads();
        // step2: gval[j] = relu(sum_kf G[v][kf]*Theta[kf][o])  — lane o holds gcn_t[v][o]
        float gval[16];
        #pragma unroll
        for (int j = 0; j < 16; ++j) {
            float s = 0.f;
            if (j < nv) {
                int v = qu + 4 * j;
                #pragma unroll
                for (int kf = 0; kf < 15; ++kf) s += sG[v * 16 + kf] * th[kf];
            }
            gval[j] = fmaxf(s, 0.f);
        }
        // step3: tc[o][v] += sum_c gcn_t[v][c]*tw[o][c][t]  — readlane broadcast, no LDS.
        // KEEP ROLLED: full unroll hoists 64 'w' loads -> VGPR explosion -> scratch spills
        // (round 1/2: 0.6-1.8 GB of scratch traffic). 1 load + 16 fma per iter is latency-fine.
        const float* twtp = twt + t * 4096;
        #pragma unroll 1
        for (int c = 0; c < 64; ++c) {
            float w = twtp[c * 64 + o];   // coalesced, L2-hot
            #pragma unroll
            for (int j = 0; j < 16; ++j)
                acc[j] += rlane(gval[j], c) * w;   // gval=0 for j>=nv
        }
    }

    // ---- epilogue: res + tc, relu, LayerNorm over o (64 lanes of wave) ----
    float rw5[5];
    #pragma unroll
    for (int f = 0; f < 5; ++f) rw5[f] = rw[o * 5 + f];
    const float rb_o = rb[o], tb_o = tb[o], gam = gamma_[o], bet = beta_[o];

    #pragma unroll
    for (int j = 0; j < 16; ++j) {
        if (j < nv) {
            int v = qu + 4 * j;
            float r = rb_o;
            #pragma unroll
            for (int f = 0; f < 5; ++f) r += sx[v * 5 + f] * rw5[f];  // x[:,0]
            float z = r + (acc[j] + tb_o) * INV_SQRT15;
            z = fmaxf(z, 0.f);
            float s1 = z, s2 = z * z;
            #pragma unroll
            for (int m = 1; m < 64; m <<= 1) {
                s1 += __shfl_xor(s1, m, 64);
                s2 += __shfl_xor(s2, m, 64);
            }
            float mean = s1 * 0.015625f;
            float var  = s2 * 0.015625f - mean * mean;
            float ov   = (z - mean) * rsqrtf(var + 1e-5f) * gam + bet;
            out[XR_OFF + (size_t)b * 3968 + v * 64 + o] = ov;
        }
    }
}

extern "C" void kernel_launch(void* const* d_in, const int* in_sizes, int n_in,
                              void* d_out, int out_size, void* d_ws, size_t ws_size,
                              hipStream_t stream) {
    const float* x   = (const float*)d_in[0];
    const float* U1  = (const float*)d_in[1];
    const float* U2  = (const float*)d_in[2];
    const float* U3  = (const float*)d_in[3];
    const float* be  = (const float*)d_in[4];
    const float* Ve  = (const float*)d_in[5];
    const float* W1  = (const float*)d_in[6];
    const float* W2  = (const float*)d_in[7];
    const float* W3  = (const float*)d_in[8];
    const float* bs  = (const float*)d_in[9];
    const float* Vs  = (const float*)d_in[10];
    const float* a   = (const float*)d_in[11];
    const float* Th  = (const float*)d_in[12];
    const float* tw  = (const float*)d_in[13];
    const float* tb  = (const float*)d_in[14];
    const float* rw  = (const float*)d_in[15];
    const float* rb  = (const float*)d_in[16];
    const float* gm  = (const float*)d_in[17];
    const float* bt  = (const float*)d_in[18];
    float* out = (float*)d_out;
    float* twt = (float*)d_ws;  // 12288 floats

    prep_kernel<<<48, 256, 0, stream>>>(tw, twt, out);
    stgcn_kernel<<<2048, 256, 0, stream>>>(x, U1, U2, U3, be, Ve, W1, W2, W3,
                                           bs, Vs, a, Th, twt, tb, rw, rb, gm, bt, out);
}

// Round 4
// 431.530 us; speedup vs baseline: 1.5056x; 1.0145x over previous
//
#include <hip/hip_runtime.h>

// Problem constants
#define BB 2048
#define TT 3
#define VV 62
#define FF 5
#define HH 64

// Output layout (flat, return order): x_residual[2048*62*64], Sloss, dloss, S[2048*62*62]
#define XR_OFF 0
#define SL_OFF 8126464
#define DL_OFF 8126465
#define S_OFF  8126466

#define ALPHA_F 1e-4f
#define INV_SQRT310 0.05679618342470648f  // 1/sqrt(62*5)
#define INV_SQRT15  0.2581988897471611f   // 1/sqrt(3*5)

// Prep: transpose tw (o,c,t) -> twt (t,c,o) in workspace, zero the two loss accumulators.
__global__ void prep_kernel(const float* __restrict__ tw, float* __restrict__ twt,
                            float* __restrict__ out) {
    int i = blockIdx.x * 256 + threadIdx.x;
    if (i < 12288) {
        int t = i >> 12, r = i & 4095, c = r >> 6, o = r & 63;
        twt[i] = tw[o * 192 + c * 3 + t];
    }
    if (i < 2) out[SL_OFF + i] = 0.f;
}

__device__ __forceinline__ float rlane(float v, int l) {
    return __int_as_float(__builtin_amdgcn_readlane(__float_as_int(v), l));
}

// Empirical law (R0-R3): effective VGPR pool = 256/EU. waves_per_eu(3,3) -> RA budget ~80,
// demand ~60-70 after gval split -> 3 waves/EU residency, no spill.
__launch_bounds__(256)
__attribute__((amdgpu_waves_per_eu(3, 3)))
__global__ void stgcn_kernel(
    const float* __restrict__ x,     const float* __restrict__ U1,
    const float* __restrict__ U2,    const float* __restrict__ U3,
    const float* __restrict__ be,    const float* __restrict__ Ve,
    const float* __restrict__ W1,    const float* __restrict__ W2,
    const float* __restrict__ W3,    const float* __restrict__ bs,
    const float* __restrict__ Vs,    const float* __restrict__ a,
    const float* __restrict__ Theta, const float* __restrict__ twt,
    const float* __restrict__ tb,    const float* __restrict__ rw,
    const float* __restrict__ rb,    const float* __restrict__ gamma_,
    const float* __restrict__ beta_, float* __restrict__ out)
{
    // LDS: 930 + 3844 + 3844 + 1132 = 9750 floats = 39000 B
    __shared__ float sx[930];    // x[b] [t][v][f]           (alive whole kernel)
    __shared__ float sS[3844];   // stage C: sigmoid(s_prod+bs); stage D/F: tmpS -> S -> C1=S*At
    __shared__ float sAt[3844];  // Sm -> spatial_At -> C2=(2S^2-I)*At
    __shared__ float sU[1132];   // union scratch (stage B/C vs stage D/F)

    // stage B/C view of sU  (x_TAt never materialized: factored via w1t / R0)
    float* const sL    = sU;          // 186  temporal lhs [t][u62] -> s_lhs [v][3]
    float* const sR    = sU + 186;    // 186  temporal rhs [v][t3]
    float* const sR0   = sU + 372;    // 186  R0[t][v] = sum_f W3[f]*x[t][v][f]
    float* const sRr   = sU + 558;    // 186  s_rhs [t][v62]
    float* const sy    = sU + 744;    // 15
    float* const sprod = sU + 759;    // 9
    float* const sE    = sU + 768;    // 9
    float* const stA   = sU + 777;    // 9
    // stage D/F view of sU (all B/C buffers dead by then)
    float* const sG    = sU;          // 992  G_t [v][16] (kf=15)
    float* const sDiag = sU + 992;    // 62   diag of spatial_At
    float* const scol  = sU + 1054;   // 62   1/colsum of tmpS
    float* const sred  = sU + 1116;   // 16   reductions

    const int b   = blockIdx.x;
    const int tid = threadIdx.x;
    const int o   = tid & 63;
    const int q   = tid >> 6;                              // wave id
    const int qu  = __builtin_amdgcn_readfirstlane(q);     // SGPR copy for uniform addressing
    const int nv  = (qu < 2) ? 16 : 15;                    // #valid v = qu + 4j

    // ---- stage A: loads ----
    for (int i = tid; i < 930; i += 256) sx[i] = x[b * 930 + i];
    __syncthreads();

    // ---- stage B: temporal attention ----
    // y[t][f] = sum_v x[t][v][f]*U1[v]
    if (tid < 15) {
        int t = tid / 5, f = tid % 5;
        float s = 0.f;
        for (int v = 0; v < 62; ++v) s += sx[t * 310 + v * 5 + f] * U1[v];
        sy[tid] = s;
    }
    // rhs[v][t] = sum_f U3[f]*x[t][v][f]; also R0[t][v] = sum_f W3[f]*x[t][v][f] (for stage C)
    if (tid < 186) {
        int v = tid / 3, t = tid % 3;
        float s = 0.f, s0 = 0.f;
        #pragma unroll
        for (int f = 0; f < 5; ++f) {
            float xv = sx[t * 310 + v * 5 + f];
            s  += U3[f] * xv;
            s0 += W3[f] * xv;
        }
        sR[v * 3 + t]  = s;
        sR0[t * 62 + v] = s0;
    }
    __syncthreads();
    // lhs[t][u] = sum_f y[t][f]*U2[f][u]
    if (tid < 186) {
        int t = tid / 62, u = tid % 62;
        float s = 0.f;
        for (int f = 0; f < 5; ++f) s += sy[t * 5 + f] * U2[f * 62 + u];
        sL[t * 62 + u] = s;
    }
    __syncthreads();
    // prod[t][u] = sum_v lhs[t][v]*rhs[v][u]
    if (tid < 9) {
        int t = tid / 3, u = tid % 3;
        float s = 0.f;
        for (int v = 0; v < 62; ++v) s += sL[t * 62 + v] * sR[v * 3 + u];
        sprod[tid] = s;
    }
    __syncthreads();
    // E[t][u] = sum_s Ve[t][s]*sigmoid(prod[s][u]+be[s][u])
    if (tid < 9) {
        int t = tid / 3, u = tid % 3;
        float s = 0.f;
        for (int ss = 0; ss < 3; ++ss) {
            float p  = sprod[ss * 3 + u] + be[ss * 3 + u];
            float sg = 1.f / (1.f + __expf(-p));
            s += Ve[t * 3 + ss] * sg;
        }
        sE[tid] = s;
    }
    __syncthreads();
    // temporal softmax over t per u
    if (tid < 3) {
        int u = tid;
        float m = -1e30f;
        for (int t = 0; t < 3; ++t) m = fmaxf(m, sE[t * 3 + u]);
        float e0 = __expf(sE[0 * 3 + u] - m);
        float e1 = __expf(sE[1 * 3 + u] - m);
        float e2 = __expf(sE[2 * 3 + u] - m);
        float inv = 1.f / (e0 + e1 + e2);
        stA[0 * 3 + u] = e0 * inv;
        stA[1 * 3 + u] = e1 * inv;
        stA[2 * 3 + u] = e2 * inv;
    }
    __syncthreads();

    // ---- stage C: spatial attention (x_TAt factored out) ----
    // s_lhs[v][s] = INV * sum_f (sum_t x[t][v][f]*w1t[t]) * W2[f][s],  w1t[t]=sum_u W1[u]*At[t][u]
    // s_rhs[u][v] = INV * sum_t At[t][u] * R0[t][v]
    if (tid < 186) {
        float w1t[3];
        #pragma unroll
        for (int t = 0; t < 3; ++t) {
            float s = 0.f;
            #pragma unroll
            for (int u = 0; u < 3; ++u) s += W1[u] * stA[t * 3 + u];
            w1t[t] = s;
        }
        int v = tid / 3, s3 = tid - v * 3;
        float s = 0.f;
        #pragma unroll
        for (int f = 0; f < 5; ++f) {
            float z = 0.f;
            #pragma unroll
            for (int t = 0; t < 3; ++t) z += sx[t * 310 + v * 5 + f] * w1t[t];
            s += z * W2[f * 3 + s3];
        }
        sL[v * 3 + s3] = s * INV_SQRT310;
        int u2 = tid / 62, v2 = tid - u2 * 62;
        float s2 = 0.f;
        #pragma unroll
        for (int t = 0; t < 3; ++t) s2 += stA[t * 3 + u2] * sR0[t * 62 + v2];
        sRr[u2 * 62 + v2] = s2 * INV_SQRT310;
    }
    __syncthreads();
    // sig[u][v] = sigmoid(sum_t s_lhs[u][t]*s_rhs[t][v] + bs[u][v])  -> into sS (dead until tmpS)
    for (int i = tid; i < 3844; i += 256) {
        int u = i / 62, v = i - u * 62;
        float s = bs[i];
        for (int t = 0; t < 3; ++t) s += sL[u * 3 + t] * sRr[t * 62 + v];
        sS[i] = 1.f / (1.f + __expf(-s));
    }
    __syncthreads();
    // Sm[u][v] = sum_w Vs[u][w]*sig[w][v]  — row-per-wave: u wave-uniform => Vs loads scalar-promotable
    if (o < 62) {
        for (int r = 0; r < nv; ++r) {
            int u = qu + 4 * r;
            const float* vr = Vs + u * 62;
            float s = 0.f;
            for (int w = 0; w < 62; ++w) s += vr[w] * sS[w * 62 + o];
            sAt[u * 62 + o] = s;
        }
    }
    __syncthreads();
    // spatial softmax over u (columns)
    if (tid < 62) {
        int v = tid;
        float m = -1e30f;
        for (int u = 0; u < 62; ++u) m = fmaxf(m, sAt[u * 62 + v]);
        float den = 0.f;
        for (int u = 0; u < 62; ++u) {
            float e = __expf(sAt[u * 62 + v] - m);
            sAt[u * 62 + v] = e;
            den += e;
        }
        float inv = 1.f / den;
        for (int u = 0; u < 62; ++u) sAt[u * 62 + v] *= inv;
    }

    // ---- stage D: S matrix, losses ----
    // tmpS[i][j] = exp(relu(sum_f |xm[i][f]-xm[j][f]|*a[f])), xm = x[:,1]  (overwrites sig in sS)
    for (int idx = tid; idx < 3844; idx += 256) {
        int i = idx / 62, j = idx - i * 62;
        float s = 0.f;
        #pragma unroll
        for (int f = 0; f < 5; ++f)
            s += fabsf(sx[310 + i * 5 + f] - sx[310 + j * 5 + f]) * a[f];
        sS[idx] = __expf(fmaxf(s, 0.f));
    }
    __syncthreads();
    if (tid < 62) {
        int j = tid;
        float s = 0.f;
        for (int i = 0; i < 62; ++i) s += sS[i * 62 + j];
        scol[j] = 1.f / s;
    }
    // dloss partial: sum_{j,f} d2 = sum_f (2*62*sum(xm^2) - 2*(sum xm)^2)
    if (tid < 5) {
        float su = 0.f, sq = 0.f;
        for (int v = 0; v < 62; ++v) {
            float xv = sx[310 + v * 5 + tid];
            su += xv; sq += xv * xv;
        }
        sred[8 + tid] = 124.f * sq - 2.f * su * su;
    }
    __syncthreads();
    // normalize S, write out, Sloss partial; fuse C1/C2 transform
    float slp = 0.f;
    for (int idx = tid; idx < 3844; idx += 256) {
        int i = idx / 62, j = idx - i * 62;
        float sv = sS[idx] * scol[j];
        out[S_OFF + (size_t)b * 3844 + idx] = sv;
        slp += sv * sv;
        float A = sAt[idx];
        if (i == j) sDiag[i] = A;
        sS[idx] = sv * A;                               // C1 = S*At
        float c2 = 2.f * sv * sv; if (i == j) c2 -= 1.f;
        sAt[idx] = c2 * A;                              // C2 = (2S^2 - I)*At
    }
    // Sloss reduce
    for (int m = 32; m > 0; m >>= 1) slp += __shfl_down(slp, m, 64);
    if ((tid & 63) == 0) sred[q] = slp;
    __syncthreads();
    if (tid == 0) {
        atomicAdd(out + SL_OFF, (sred[0] + sred[1] + sred[2] + sred[3]) * (ALPHA_F / 2048.f));
        float dl = sred[8] + sred[9] + sred[10] + sred[11] + sred[12];
        atomicAdd(out + DL_OFF, dl * ALPHA_F);
    }

    // ---- stage F: spatial GCN + temporal conv, gcn tile in regs + readlane ----
    float th[15];                                          // Theta[kf][o] in regs
    #pragma unroll
    for (int kf = 0; kf < 15; ++kf) th[kf] = Theta[kf * 64 + o];

    float acc[16];
    #pragma unroll
    for (int j = 0; j < 16; ++j) acc[j] = 0.f;

    for (int t = 0; t < 3; ++t) {
        __syncthreads();
        // step1: G_t[v][kf]  (kf = k*5+f, k in {0,1,2})
        for (int i = tid; i < 310; i += 256) {
            int v = i / 5, f = i - v * 5;
            float g0 = sDiag[v] * sx[t * 310 + i];
            float g1 = 0.f, g2 = 0.f;
            for (int u = 0; u < 62; ++u) {
                float xa = sx[t * 310 + u * 5 + f];
                g1 -= sS[u * 62 + v] * xa;   // cheb1 = -S
                g2 += sAt[u * 62 + v] * xa;  // cheb2 = 2S^2 - I
            }
            sG[v * 16 + f]      = g0;
            sG[v * 16 + 5 + f]  = g1;
            sG[v * 16 + 10 + f] = g2;
        }
        __syncthreads();
        // steps 2+3 in two j-halves of 8: peak VGPR = acc16+gval8+th15 (~60 demand, fits 80 budget).
        // c-loop KEPT ROLLED (full unroll hoists 64 'w' loads -> spills; R1/R2 evidence).
        const float* twtp = twt + t * 4096;
        #pragma unroll
        for (int half = 0; half < 2; ++half) {
            float gval[8];
            #pragma unroll
            for (int jj = 0; jj < 8; ++jj) {
                int j = half * 8 + jj;
                float s = 0.f;
                if (j < nv) {
                    int v = qu + 4 * j;
                    #pragma unroll
                    for (int kf = 0; kf < 15; ++kf) s += sG[v * 16 + kf] * th[kf];
                }
                gval[jj] = fmaxf(s, 0.f);
            }
            #pragma unroll 1
            for (int c = 0; c < 64; ++c) {
                float w = twtp[c * 64 + o];   // coalesced, L1-hot
                #pragma unroll
                for (int jj = 0; jj < 8; ++jj)
                    acc[half * 8 + jj] += rlane(gval[jj], c) * w;   // gval=0 for j>=nv
            }
        }
    }

    // ---- epilogue: res + tc, relu, LayerNorm over o (64 lanes of wave) ----
    float rw5[5];
    #pragma unroll
    for (int f = 0; f < 5; ++f) rw5[f] = rw[o * 5 + f];
    const float rb_o = rb[o], tb_o = tb[o], gam = gamma_[o], bet = beta_[o];

    #pragma unroll
    for (int j = 0; j < 16; ++j) {
        if (j < nv) {
            int v = qu + 4 * j;
            float r = rb_o;
            #pragma unroll
            for (int f = 0; f < 5; ++f) r += sx[v * 5 + f] * rw5[f];  // x[:,0]
            float z = r + (acc[j] + tb_o) * INV_SQRT15;
            z = fmaxf(z, 0.f);
            float s1 = z, s2 = z * z;
            #pragma unroll
            for (int m = 1; m < 64; m <<= 1) {
                s1 += __shfl_xor(s1, m, 64);
                s2 += __shfl_xor(s2, m, 64);
            }
            float mean = s1 * 0.015625f;
            float var  = s2 * 0.015625f - mean * mean;
            float ov   = (z - mean) * rsqrtf(var + 1e-5f) * gam + bet;
            out[XR_OFF + (size_t)b * 3968 + v * 64 + o] = ov;
        }
    }
}

extern "C" void kernel_launch(void* const* d_in, const int* in_sizes, int n_in,
                              void* d_out, int out_size, void* d_ws, size_t ws_size,
                              hipStream_t stream) {
    const float* x   = (const float*)d_in[0];
    const float* U1  = (const float*)d_in[1];
    const float* U2  = (const float*)d_in[2];
    const float* U3  = (const float*)d_in[3];
    const float* be  = (const float*)d_in[4];
    const float* Ve  = (const float*)d_in[5];
    const float* W1  = (const float*)d_in[6];
    const float* W2  = (const float*)d_in[7];
    const float* W3  = (const float*)d_in[8];
    const float* bs  = (const float*)d_in[9];
    const float* Vs  = (const float*)d_in[10];
    const float* a   = (const float*)d_in[11];
    const float* Th  = (const float*)d_in[12];
    const float* tw  = (const float*)d_in[13];
    const float* tb  = (const float*)d_in[14];
    const float* rw  = (const float*)d_in[15];
    const float* rb  = (const float*)d_in[16];
    const float* gm  = (const float*)d_in[17];
    const float* bt  = (const float*)d_in[18];
    float* out = (float*)d_out;
    float* twt = (float*)d_ws;  // 12288 floats

    prep_kernel<<<48, 256, 0, stream>>>(tw, twt, out);
    stgcn_kernel<<<2048, 256, 0, stream>>>(x, U1, U2, U3, be, Ve, W1, W2, W3,
                                           bs, Vs, a, Th, twt, tb, rw, rb, gm, bt, out);
}

// Round 5
// 350.872 us; speedup vs baseline: 1.8517x; 1.2299x over previous
//
#include <hip/hip_runtime.h>

// Problem constants
#define BB 2048
#define TT 3
#define VV 62
#define FF 5
#define HH 64

// Output layout (flat, return order): x_residual[2048*62*64], Sloss, dloss, S[2048*62*62]
#define XR_OFF 0
#define SL_OFF 8126464
#define DL_OFF 8126465
#define S_OFF  8126466

#define ALPHA_F 1e-4f
#define INV_SQRT310 0.05679618342470648f  // 1/sqrt(62*5)
#define INV_SQRT15  0.2581988897471611f   // 1/sqrt(3*5)

// Prep: transpose tw (o,c,t) -> twt (t,c,o) in workspace, zero the two loss accumulators.
__global__ void prep_kernel(const float* __restrict__ tw, float* __restrict__ twt,
                            float* __restrict__ out) {
    int i = blockIdx.x * 256 + threadIdx.x;
    if (i < 12288) {
        int t = i >> 12, r = i & 4095, c = r >> 6, o = r & 63;
        twt[i] = tw[o * 192 + c * 3 + t];
    }
    if (i < 2) out[SL_OFF + i] = 0.f;
}

// LDS 54872B -> 2 blocks/CU. R3/R4 evidence: duration is occupancy-insensitive, so trade
// residency for the step3 lane-swap that kills 3072 readlanes/thread.
__launch_bounds__(256, 2)
__global__ void stgcn_kernel(
    const float* __restrict__ x,     const float* __restrict__ U1,
    const float* __restrict__ U2,    const float* __restrict__ U3,
    const float* __restrict__ be,    const float* __restrict__ Ve,
    const float* __restrict__ W1,    const float* __restrict__ W2,
    const float* __restrict__ W3,    const float* __restrict__ bs,
    const float* __restrict__ Vs,    const float* __restrict__ a,
    const float* __restrict__ Theta, const float* __restrict__ twt,
    const float* __restrict__ tb,    const float* __restrict__ rw,
    const float* __restrict__ rb,    const float* __restrict__ gamma_,
    const float* __restrict__ beta_, float* __restrict__ out)
{
    // LDS: 930 + 3844 + 3844 + 1132 + 3968 = 13718 floats = 54872 B
    __shared__ float sx[930];    // x[b] [t][v][f]           (alive whole kernel)
    __shared__ float sS[3844];   // stage C: sigmoid(s_prod+bs); stage D/F: tmpS -> S -> C1=S*At
    __shared__ float sAt[3844];  // Sm -> spatial_At -> C2=(2S^2-I)*At
    __shared__ float sU[1132];   // union scratch (stage B/C vs stage D/F)
    __shared__ float sP[3968];   // stage F: swizzled gcn[v][c] per t; then z[v][o]

    // stage B/C view of sU  (x_TAt never materialized: factored via w1t / R0)
    float* const sL    = sU;          // 186  temporal lhs [t][u62] -> s_lhs [v][3]
    float* const sR    = sU + 186;    // 186  temporal rhs [v][t3]
    float* const sR0   = sU + 372;    // 186  R0[t][v] = sum_f W3[f]*x[t][v][f]
    float* const sRr   = sU + 558;    // 186  s_rhs [t][v62]
    float* const sy    = sU + 744;    // 15
    float* const sprod = sU + 759;    // 9
    float* const sE    = sU + 768;    // 9
    float* const stA   = sU + 777;    // 9
    // stage D/F view of sU (all B/C buffers dead by then)
    float* const sG    = sU;          // 992  G_t [v][16] (kf=15, slot15 unused)
    float* const sDiag = sU + 992;    // 62   diag of spatial_At
    float* const scol  = sU + 1054;   // 62   1/colsum of tmpS
    float* const sred  = sU + 1116;   // 16   reductions

    const int b   = blockIdx.x;
    const int tid = threadIdx.x;
    const int o   = tid & 63;
    const int q   = tid >> 6;                              // wave id
    const int qu  = __builtin_amdgcn_readfirstlane(q);     // SGPR copy for uniform addressing
    const int nv  = (qu < 2) ? 16 : 15;                    // #valid v = qu + 4j

    // ---- stage A: loads ----
    for (int i = tid; i < 930; i += 256) sx[i] = x[b * 930 + i];
    __syncthreads();

    // ---- stage B: temporal attention ----
    // y[t][f] = sum_v x[t][v][f]*U1[v]
    if (tid < 15) {
        int t = tid / 5, f = tid % 5;
        float s = 0.f;
        for (int v = 0; v < 62; ++v) s += sx[t * 310 + v * 5 + f] * U1[v];
        sy[tid] = s;
    }
    // rhs[v][t] = sum_f U3[f]*x[t][v][f]; also R0[t][v] = sum_f W3[f]*x[t][v][f] (for stage C)
    if (tid < 186) {
        int v = tid / 3, t = tid % 3;
        float s = 0.f, s0 = 0.f;
        #pragma unroll
        for (int f = 0; f < 5; ++f) {
            float xv = sx[t * 310 + v * 5 + f];
            s  += U3[f] * xv;
            s0 += W3[f] * xv;
        }
        sR[v * 3 + t]  = s;
        sR0[t * 62 + v] = s0;
    }
    __syncthreads();
    // lhs[t][u] = sum_f y[t][f]*U2[f][u]
    if (tid < 186) {
        int t = tid / 62, u = tid % 62;
        float s = 0.f;
        for (int f = 0; f < 5; ++f) s += sy[t * 5 + f] * U2[f * 62 + u];
        sL[t * 62 + u] = s;
    }
    __syncthreads();
    // prod[t][u] = sum_v lhs[t][v]*rhs[v][u]
    if (tid < 9) {
        int t = tid / 3, u = tid % 3;
        float s = 0.f;
        for (int v = 0; v < 62; ++v) s += sL[t * 62 + v] * sR[v * 3 + u];
        sprod[tid] = s;
    }
    __syncthreads();
    // E[t][u] = sum_s Ve[t][s]*sigmoid(prod[s][u]+be[s][u])
    if (tid < 9) {
        int t = tid / 3, u = tid % 3;
        float s = 0.f;
        for (int ss = 0; ss < 3; ++ss) {
            float p  = sprod[ss * 3 + u] + be[ss * 3 + u];
            float sg = 1.f / (1.f + __expf(-p));
            s += Ve[t * 3 + ss] * sg;
        }
        sE[tid] = s;
    }
    __syncthreads();
    // temporal softmax over t per u
    if (tid < 3) {
        int u = tid;
        float m = -1e30f;
        for (int t = 0; t < 3; ++t) m = fmaxf(m, sE[t * 3 + u]);
        float e0 = __expf(sE[0 * 3 + u] - m);
        float e1 = __expf(sE[1 * 3 + u] - m);
        float e2 = __expf(sE[2 * 3 + u] - m);
        float inv = 1.f / (e0 + e1 + e2);
        stA[0 * 3 + u] = e0 * inv;
        stA[1 * 3 + u] = e1 * inv;
        stA[2 * 3 + u] = e2 * inv;
    }
    __syncthreads();

    // ---- stage C: spatial attention (x_TAt factored out) ----
    if (tid < 186) {
        float w1t[3];
        #pragma unroll
        for (int t = 0; t < 3; ++t) {
            float s = 0.f;
            #pragma unroll
            for (int u = 0; u < 3; ++u) s += W1[u] * stA[t * 3 + u];
            w1t[t] = s;
        }
        int v = tid / 3, s3 = tid - v * 3;
        float s = 0.f;
        #pragma unroll
        for (int f = 0; f < 5; ++f) {
            float z = 0.f;
            #pragma unroll
            for (int t = 0; t < 3; ++t) z += sx[t * 310 + v * 5 + f] * w1t[t];
            s += z * W2[f * 3 + s3];
        }
        sL[v * 3 + s3] = s * INV_SQRT310;
        int u2 = tid / 62, v2 = tid - u2 * 62;
        float s2 = 0.f;
        #pragma unroll
        for (int t = 0; t < 3; ++t) s2 += stA[t * 3 + u2] * sR0[t * 62 + v2];
        sRr[u2 * 62 + v2] = s2 * INV_SQRT310;
    }
    __syncthreads();
    // sig[u][v] = sigmoid(sum_t s_lhs[u][t]*s_rhs[t][v] + bs[u][v])  -> into sS
    for (int i = tid; i < 3844; i += 256) {
        int u = i / 62, v = i - u * 62;
        float s = bs[i];
        for (int t = 0; t < 3; ++t) s += sL[u * 3 + t] * sRr[t * 62 + v];
        sS[i] = 1.f / (1.f + __expf(-s));
    }
    __syncthreads();
    // Sm[u][v] = sum_w Vs[u][w]*sig[w][v]  — row-per-wave: u wave-uniform => Vs scalar loads
    if (o < 62) {
        for (int r = 0; r < nv; ++r) {
            int u = qu + 4 * r;
            const float* vr = Vs + u * 62;
            float s = 0.f;
            for (int w = 0; w < 62; ++w) s += vr[w] * sS[w * 62 + o];
            sAt[u * 62 + o] = s;
        }
    }
    __syncthreads();
    // spatial softmax over u (columns)
    if (tid < 62) {
        int v = tid;
        float m = -1e30f;
        for (int u = 0; u < 62; ++u) m = fmaxf(m, sAt[u * 62 + v]);
        float den = 0.f;
        for (int u = 0; u < 62; ++u) {
            float e = __expf(sAt[u * 62 + v] - m);
            sAt[u * 62 + v] = e;
            den += e;
        }
        float inv = 1.f / den;
        for (int u = 0; u < 62; ++u) sAt[u * 62 + v] *= inv;
    }

    // ---- stage D: S matrix, losses ----
    for (int idx = tid; idx < 3844; idx += 256) {
        int i = idx / 62, j = idx - i * 62;
        float s = 0.f;
        #pragma unroll
        for (int f = 0; f < 5; ++f)
            s += fabsf(sx[310 + i * 5 + f] - sx[310 + j * 5 + f]) * a[f];
        sS[idx] = __expf(fmaxf(s, 0.f));
    }
    __syncthreads();
    if (tid < 62) {
        int j = tid;
        float s = 0.f;
        for (int i = 0; i < 62; ++i) s += sS[i * 62 + j];
        scol[j] = 1.f / s;
    }
    // dloss partial: sum_{j,f} d2 = sum_f (2*62*sum(xm^2) - 2*(sum xm)^2)
    if (tid < 5) {
        float su = 0.f, sq = 0.f;
        for (int v = 0; v < 62; ++v) {
            float xv = sx[310 + v * 5 + tid];
            su += xv; sq += xv * xv;
        }
        sred[8 + tid] = 124.f * sq - 2.f * su * su;
    }
    __syncthreads();
    // normalize S, write out, Sloss partial; fuse C1/C2 transform
    float slp = 0.f;
    for (int idx = tid; idx < 3844; idx += 256) {
        int i = idx / 62, j = idx - i * 62;
        float sv = sS[idx] * scol[j];
        out[S_OFF + (size_t)b * 3844 + idx] = sv;
        slp += sv * sv;
        float A = sAt[idx];
        if (i == j) sDiag[i] = A;
        sS[idx] = sv * A;                               // C1 = S*At
        float c2 = 2.f * sv * sv; if (i == j) c2 -= 1.f;
        sAt[idx] = c2 * A;                              // C2 = (2S^2 - I)*At
    }
    // Sloss reduce
    for (int m = 32; m > 0; m >>= 1) slp += __shfl_down(slp, m, 64);
    if ((tid & 63) == 0) sred[q] = slp;
    __syncthreads();
    if (tid == 0) {
        atomicAdd(out + SL_OFF, (sred[0] + sred[1] + sred[2] + sred[3]) * (ALPHA_F / 2048.f));
        float dl = sred[8] + sred[9] + sred[10] + sred[11] + sred[12];
        atomicAdd(out + DL_OFF, dl * ALPHA_F);
    }

    // ---- stage F: spatial GCN + temporal conv ----
    float th[15];                                          // Theta[kf][o] in regs
    #pragma unroll
    for (int kf = 0; kf < 15; ++kf) th[kf] = Theta[kf * 64 + o];

    const int vlane = o;           // step3/z-phase role: lane index is v
    const int qo    = qu * 16;     // this wave's o-chunk
    const int swz   = vlane & 31;

    float acc2[16];                // acc2[m] = tc[v=vlane][o=qo+m]
    #pragma unroll
    for (int m = 0; m < 16; ++m) acc2[m] = 0.f;

    for (int t = 0; t < 3; ++t) {
        __syncthreads();
        // step1: G_t[v][kf]  (kf = k*5+f, k in {0,1,2})
        for (int i = tid; i < 310; i += 256) {
            int v = i / 5, f = i - v * 5;
            float g0 = sDiag[v] * sx[t * 310 + i];
            float g1 = 0.f, g2 = 0.f;
            for (int u = 0; u < 62; ++u) {
                float xa = sx[t * 310 + u * 5 + f];
                g1 -= sS[u * 62 + v] * xa;   // cheb1 = -S
                g2 += sAt[u * 62 + v] * xa;  // cheb2 = 2S^2 - I
            }
            sG[v * 16 + f]      = g0;
            sG[v * 16 + 5 + f]  = g1;
            sG[v * 16 + 10 + f] = g2;
        }
        __syncthreads();
        // step2: lane o computes gcn[v][o] via 4x ds_read_b128; write XOR-swizzled sP.
        // Swizzle makes BOTH this write (lanes=o, v uniform) and step3's read
        // (lanes=v, c uniform) conflict-free.
        #pragma unroll 2
        for (int j = 0; j < 16; ++j) {
            if (j < nv) {
                int v = qu + 4 * j;
                const float4* g4 = reinterpret_cast<const float4*>(sG + v * 16);
                float4 a0 = g4[0], a1 = g4[1], a2 = g4[2], a3 = g4[3];
                float s = a0.x*th[0]  + a0.y*th[1]  + a0.z*th[2]  + a0.w*th[3]
                        + a1.x*th[4]  + a1.y*th[5]  + a1.z*th[6]  + a1.w*th[7]
                        + a2.x*th[8]  + a2.y*th[9]  + a2.z*th[10] + a2.w*th[11]
                        + a3.x*th[12] + a3.y*th[13] + a3.z*th[14];  // slot15 unused
                sP[v * 64 + (o ^ (v & 31))] = fmaxf(s, 0.f);
            }
        }
        __syncthreads();
        // step3: lane=v; per c: 1 LDS read + 4 wave-uniform float4 twt loads (SMEM)
        // + 16 fma. No readlanes, no per-lane VMEM.
        const float* twtp = twt + t * 4096;
        #pragma unroll 2
        for (int c = 0; c < 64; ++c) {
            float g = sP[vlane * 64 + (c ^ swz)];
            const float4* wr = reinterpret_cast<const float4*>(twtp + c * 64 + qo);
            float4 w0 = wr[0], w1 = wr[1], w2 = wr[2], w3 = wr[3];
            acc2[0]  += g * w0.x;  acc2[1]  += g * w0.y;
            acc2[2]  += g * w0.z;  acc2[3]  += g * w0.w;
            acc2[4]  += g * w1.x;  acc2[5]  += g * w1.y;
            acc2[6]  += g * w1.z;  acc2[7]  += g * w1.w;
            acc2[8]  += g * w2.x;  acc2[9]  += g * w2.y;
            acc2[10] += g * w2.z;  acc2[11] += g * w2.w;
            acc2[12] += g * w3.x;  acc2[13] += g * w3.y;
            acc2[14] += g * w3.z;  acc2[15] += g * w3.w;
        }
    }

    // ---- z-phase: lane=v computes z[v][qo+m] (res uniform-scalar loads), stage in sP ----
    __syncthreads();
    if (vlane < 62) {
        float x5[5];
        #pragma unroll
        for (int f = 0; f < 5; ++f) x5[f] = sx[vlane * 5 + f];   // x[:,0]
        #pragma unroll
        for (int m = 0; m < 16; ++m) {
            int oo = qo + m;
            float r = rb[oo];
            #pragma unroll
            for (int f = 0; f < 5; ++f) r += x5[f] * rw[oo * 5 + f];
            float z = r + (acc2[m] + tb[oo]) * INV_SQRT15;
            sP[vlane * 64 + (oo ^ swz)] = fmaxf(z, 0.f);
        }
    }
    __syncthreads();

    // ---- epilogue: lane=o, LayerNorm over o (64 lanes of wave) ----
    const float gam = gamma_[o], bet = beta_[o];
    #pragma unroll
    for (int j = 0; j < 16; ++j) {
        if (j < nv) {
            int v = qu + 4 * j;
            float z = sP[v * 64 + (o ^ (v & 31))];
            float s1 = z, s2 = z * z;
            #pragma unroll
            for (int m = 1; m < 64; m <<= 1) {
                s1 += __shfl_xor(s1, m, 64);
                s2 += __shfl_xor(s2, m, 64);
            }
            float mean = s1 * 0.015625f;
            float var  = s2 * 0.015625f - mean * mean;
            float ov   = (z - mean) * rsqrtf(var + 1e-5f) * gam + bet;
            out[XR_OFF + (size_t)b * 3968 + v * 64 + o] = ov;
        }
    }
}

extern "C" void kernel_launch(void* const* d_in, const int* in_sizes, int n_in,
                              void* d_out, int out_size, void* d_ws, size_t ws_size,
                              hipStream_t stream) {
    const float* x   = (const float*)d_in[0];
    const float* U1  = (const float*)d_in[1];
    const float* U2  = (const float*)d_in[2];
    const float* U3  = (const float*)d_in[3];
    const float* be  = (const float*)d_in[4];
    const float* Ve  = (const float*)d_in[5];
    const float* W1  = (const float*)d_in[6];
    const float* W2  = (const float*)d_in[7];
    const float* W3  = (const float*)d_in[8];
    const float* bs  = (const float*)d_in[9];
    const float* Vs  = (const float*)d_in[10];
    const float* a   = (const float*)d_in[11];
    const float* Th  = (const float*)d_in[12];
    const float* tw  = (const float*)d_in[13];
    const float* tb  = (const float*)d_in[14];
    const float* rw  = (const float*)d_in[15];
    const float* rb  = (const float*)d_in[16];
    const float* gm  = (const float*)d_in[17];
    const float* bt  = (const float*)d_in[18];
    float* out = (float*)d_out;
    float* twt = (float*)d_ws;  // 12288 floats

    prep_kernel<<<48, 256, 0, stream>>>(tw, twt, out);
    stgcn_kernel<<<2048, 256, 0, stream>>>(x, U1, U2, U3, be, Ve, W1, W2, W3,
                                           bs, Vs, a, Th, twt, tb, rw, rb, gm, bt, out);
}

// Round 6
// 345.768 us; speedup vs baseline: 1.8791x; 1.0148x over previous
//
#include <hip/hip_runtime.h>

// Problem constants
#define BB 2048
#define TT 3
#define VV 62
#define FF 5
#define HH 64

// Output layout (flat, return order): x_residual[2048*62*64], Sloss, dloss, S[2048*62*62]
#define XR_OFF 0
#define SL_OFF 8126464
#define DL_OFF 8126465
#define S_OFF  8126466

#define ALPHA_F 1e-4f
#define INV_SQRT310 0.05679618342470648f  // 1/sqrt(62*5)
#define INV_SQRT15  0.2581988897471611f   // 1/sqrt(3*5)

typedef float f32x2 __attribute__((ext_vector_type(2)));   // -> v_pk_fma_f32

// Prep: transpose tw (o,c,t) -> twt (t,c,o) in workspace, zero the two loss accumulators.
__global__ void prep_kernel(const float* __restrict__ tw, float* __restrict__ twt,
                            float* __restrict__ out) {
    int i = blockIdx.x * 256 + threadIdx.x;
    if (i < 12288) {
        int t = i >> 12, r = i & 4095, c = r >> 6, o = r & 63;
        twt[i] = tw[o * 192 + c * 3 + t];
    }
    if (i < 2) out[SL_OFF + i] = 0.f;
}

__launch_bounds__(256, 2)
__global__ void stgcn_kernel(
    const float* __restrict__ x,     const float* __restrict__ U1,
    const float* __restrict__ U2,    const float* __restrict__ U3,
    const float* __restrict__ be,    const float* __restrict__ Ve,
    const float* __restrict__ W1,    const float* __restrict__ W2,
    const float* __restrict__ W3,    const float* __restrict__ bs,
    const float* __restrict__ Vs,    const float* __restrict__ a,
    const float* __restrict__ Theta, const float* __restrict__ twt,
    const float* __restrict__ tb,    const float* __restrict__ rw,
    const float* __restrict__ rb,    const float* __restrict__ gamma_,
    const float* __restrict__ beta_, float* __restrict__ out)
{
    // LDS: 930 + 3844 + 3844 + 1132 + 3968 = 13718 floats = 54872 B
    __shared__ float sx[930];    // x[b] [t][v][f]           (alive whole kernel)
    __shared__ float sS[3844];   // sig -> tmpS -> C1n = -S*At
    __shared__ float sAt[3844];  // Sm(raw) -> C2=(2S^2-I)*At
    __shared__ float sU[1132];   // union scratch (stage B/C vs stage D/F)
    __shared__ float sP[3968];   // softmax/colsum partials; stage F gcn swizzled; z

    // stage B/C view of sU
    float* const sL    = sU;          // 186  temporal lhs -> s_lhs [v][3]
    float* const sR    = sU + 186;    // 186  temporal rhs [v][t3]
    float* const sR0   = sU + 372;    // 186  R0[t][v] = sum_f W3[f]*x[t][v][f]
    float* const sRr   = sU + 558;    // 186  s_rhs [t][v62]
    float* const sy    = sU + 744;    // 15
    float* const sprod = sU + 759;    // 9
    float* const sE    = sU + 768;    // 9
    float* const stA   = sU + 777;    // 9
    // stage D/F view of sU
    float* const sG    = sU;          // 992  G_t [v][16] (kf=15, slot15 unused)
    float* const sDiag = sU + 992;    // 62   diag of spatial_At
    float* const scol  = sU + 1054;   // 62   1/colsum of tmpS
    float* const sred  = sU + 1116;   // 16   reductions

    const int b   = blockIdx.x;
    const int tid = threadIdx.x;
    const int o   = tid & 63;
    const int q   = tid >> 6;                              // wave id
    const int qu  = __builtin_amdgcn_readfirstlane(q);     // SGPR copy
    const int nv  = (qu < 2) ? 16 : 15;                    // #valid v = qu + 4j

    // ---- stage A: loads ----
    for (int i = tid; i < 930; i += 256) sx[i] = x[b * 930 + i];
    __syncthreads();

    // ---- stage B: temporal attention ----
    if (tid < 15) {
        int t = tid / 5, f = tid % 5;
        float s = 0.f;
        for (int v = 0; v < 62; ++v) s += sx[t * 310 + v * 5 + f] * U1[v];
        sy[tid] = s;
    }
    if (tid < 186) {
        int v = tid / 3, t = tid % 3;
        float s = 0.f, s0 = 0.f;
        #pragma unroll
        for (int f = 0; f < 5; ++f) {
            float xv = sx[t * 310 + v * 5 + f];
            s  += U3[f] * xv;
            s0 += W3[f] * xv;
        }
        sR[v * 3 + t]  = s;
        sR0[t * 62 + v] = s0;
    }
    __syncthreads();
    if (tid < 186) {
        int t = tid / 62, u = tid % 62;
        float s = 0.f;
        for (int f = 0; f < 5; ++f) s += sy[t * 5 + f] * U2[f * 62 + u];
        sL[t * 62 + u] = s;
    }
    __syncthreads();
    if (tid < 9) {
        int t = tid / 3, u = tid % 3;
        float s = 0.f;
        for (int v = 0; v < 62; ++v) s += sL[t * 62 + v] * sR[v * 3 + u];
        sprod[tid] = s;
    }
    __syncthreads();
    if (tid < 9) {
        int t = tid / 3, u = tid % 3;
        float s = 0.f;
        for (int ss = 0; ss < 3; ++ss) {
            float p  = sprod[ss * 3 + u] + be[ss * 3 + u];
            float sg = 1.f / (1.f + __expf(-p));
            s += Ve[t * 3 + ss] * sg;
        }
        sE[tid] = s;
    }
    __syncthreads();
    if (tid < 3) {
        int u = tid;
        float m = -1e30f;
        for (int t = 0; t < 3; ++t) m = fmaxf(m, sE[t * 3 + u]);
        float e0 = __expf(sE[0 * 3 + u] - m);
        float e1 = __expf(sE[1 * 3 + u] - m);
        float e2 = __expf(sE[2 * 3 + u] - m);
        float inv = 1.f / (e0 + e1 + e2);
        stA[0 * 3 + u] = e0 * inv;
        stA[1 * 3 + u] = e1 * inv;
        stA[2 * 3 + u] = e2 * inv;
    }
    __syncthreads();

    // ---- stage C: spatial attention (x_TAt factored out) ----
    if (tid < 186) {
        float w1t[3];
        #pragma unroll
        for (int t = 0; t < 3; ++t) {
            float s = 0.f;
            #pragma unroll
            for (int u = 0; u < 3; ++u) s += W1[u] * stA[t * 3 + u];
            w1t[t] = s;
        }
        int v = tid / 3, s3 = tid - v * 3;
        float s = 0.f;
        #pragma unroll
        for (int f = 0; f < 5; ++f) {
            float z = 0.f;
            #pragma unroll
            for (int t = 0; t < 3; ++t) z += sx[t * 310 + v * 5 + f] * w1t[t];
            s += z * W2[f * 3 + s3];
        }
        sL[v * 3 + s3] = s * INV_SQRT310;
        int u2 = tid / 62, v2 = tid - u2 * 62;
        float s2 = 0.f;
        #pragma unroll
        for (int t = 0; t < 3; ++t) s2 += stA[t * 3 + u2] * sR0[t * 62 + v2];
        sRr[u2 * 62 + v2] = s2 * INV_SQRT310;
    }
    __syncthreads();
    // sig[u][v] -> sS
    for (int i = tid; i < 3844; i += 256) {
        int u = i / 62, v = i - u * 62;
        float s = bs[i];
        for (int t = 0; t < 3; ++t) s += sL[u * 3 + t] * sRr[t * 62 + v];
        sS[i] = 1.f / (1.f + __expf(-s));
    }
    __syncthreads();
    // Sm[u][v] = sum_w Vs[u][w]*sig[w][v]  — pk-packed over w pairs; u wave-uniform
    if (o < 62) {
        for (int r = 0; r < nv; ++r) {
            int u = qu + 4 * r;
            const float* vr = Vs + u * 62;
            f32x2 s2 = {0.f, 0.f};
            for (int w = 0; w < 62; w += 2) {
                f32x2 vv; vv.x = vr[w];            vv.y = vr[w + 1];
                f32x2 ss; ss.x = sS[w * 62 + o];   ss.y = sS[(w + 1) * 62 + o];
                s2 += vv * ss;
            }
            sAt[u * 62 + o] = s2.x + s2.y;   // RAW Sm (softmax deferred to normalize loop)
        }
    }
    __syncthreads();

    // ---- phase 2: tmpS (column-mapped, colsum partial free) + softmax col-stats + dloss ----
    {
        int j = o;
        if (j < 62) {
            int i0 = qu * 16, i1 = (qu == 3) ? 62 : i0 + 16;
            // softmax column stats over raw Sm (local max + local sum)
            float mq = -1e30f;
            for (int u = i0; u < i1; ++u) mq = fmaxf(mq, sAt[u * 62 + j]);
            float sq = 0.f;
            for (int u = i0; u < i1; ++u) sq += __expf(sAt[u * 62 + j] - mq);
            sP[qu * 64 + j]       = mq;
            sP[256 + qu * 64 + j] = sq;
            // tmpS rows i0..i1 for column j, accumulating colsum partial
            float xj[5];
            #pragma unroll
            for (int f = 0; f < 5; ++f) xj[f] = sx[310 + j * 5 + f];
            float cp = 0.f;
            for (int i = i0; i < i1; ++i) {
                float s = 0.f;
                #pragma unroll
                for (int f = 0; f < 5; ++f)
                    s += fabsf(sx[310 + i * 5 + f] - xj[f]) * a[f];
                float e = __expf(fmaxf(s, 0.f));
                sS[i * 62 + j] = e;
                cp += e;
            }
            sP[512 + qu * 64 + j] = cp;
        } else {
            // dloss partials on otherwise-idle lanes (o==62: f=wave; o==63,w0: f=4)
            int f = (o == 62) ? qu : (qu == 0 ? 4 : -1);
            if (f >= 0) {
                float su = 0.f, sq2 = 0.f;
                for (int v = 0; v < 62; ++v) {
                    float xv = sx[310 + v * 5 + f];
                    su += xv; sq2 += xv * xv;
                }
                sred[8 + f] = 124.f * sq2 - 2.f * su * su;
            }
        }
    }
    __syncthreads();
    // ---- phase 3: per-column combines (tiny) ----
    if (tid < 62) {
        int v = tid;
        float m0 = sP[v], m1 = sP[64 + v], m2 = sP[128 + v], m3 = sP[192 + v];
        float M = fmaxf(fmaxf(m0, m1), fmaxf(m2, m3));
        float den = sP[256 + v] * __expf(m0 - M) + sP[320 + v] * __expf(m1 - M)
                  + sP[384 + v] * __expf(m2 - M) + sP[448 + v] * __expf(m3 - M);
        sP[768 + v] = M;
        sP[832 + v] = 1.f / den;
        scol[v] = 1.f / (sP[512 + v] + sP[576 + v] + sP[640 + v] + sP[704 + v]);
    }
    __syncthreads();
    // ---- phase 4: normalize S, fused softmax-At, C1n/C2, Sloss ----
    float slp = 0.f;
    for (int idx = tid; idx < 3844; idx += 256) {
        int i = idx / 62, j = idx - i * 62;
        float sv = sS[idx] * scol[j];
        out[S_OFF + (size_t)b * 3844 + idx] = sv;
        slp += sv * sv;
        float A = __expf(sAt[idx] - sP[768 + j]) * sP[832 + j];   // softmaxed At on the fly
        if (i == j) sDiag[i] = A;
        sS[idx] = -sv * A;                              // C1 PRE-NEGATED (pk step1)
        float c2 = 2.f * sv * sv; if (i == j) c2 -= 1.f;
        sAt[idx] = c2 * A;                              // C2 = (2S^2 - I)*At
    }
    for (int m = 32; m > 0; m >>= 1) slp += __shfl_down(slp, m, 64);
    if ((tid & 63) == 0) sred[q] = slp;
    __syncthreads();
    if (tid == 0) {
        atomicAdd(out + SL_OFF, (sred[0] + sred[1] + sred[2] + sred[3]) * (ALPHA_F / 2048.f));
        float dl = sred[8] + sred[9] + sred[10] + sred[11] + sred[12];
        atomicAdd(out + DL_OFF, dl * ALPHA_F);
    }

    // ---- stage F: spatial GCN + temporal conv (pk-packed) ----
    f32x2 th2[7]; float th14;
    #pragma unroll
    for (int p = 0; p < 7; ++p) {
        th2[p].x = Theta[(2 * p) * 64 + o];
        th2[p].y = Theta[(2 * p + 1) * 64 + o];
    }
    th14 = Theta[14 * 64 + o];

    const int vlane = o;           // step3/z-phase lane role: v
    const int qo    = qu * 16;     // this wave's o-chunk
    const int swz   = vlane & 31;

    f32x2 accv[8];                 // accv[p] = tc[v=vlane][o=qo+2p, qo+2p+1]
    #pragma unroll
    for (int m = 0; m < 8; ++m) accv[m] = (f32x2){0.f, 0.f};

    for (int t = 0; t < 3; ++t) {
        __syncthreads();
        // step1: pk over {C1n, C2}
        for (int i = tid; i < 310; i += 256) {
            int v = i / 5, f = i - v * 5;
            float g0 = sDiag[v] * sx[t * 310 + i];
            f32x2 g12 = {0.f, 0.f};
            for (int u = 0; u < 62; ++u) {
                float xa = sx[t * 310 + u * 5 + f];
                f32x2 cc; cc.x = sS[u * 62 + v]; cc.y = sAt[u * 62 + v];
                g12 += cc * (f32x2){xa, xa};
            }
            sG[v * 16 + f]      = g0;
            sG[v * 16 + 5 + f]  = g12.x;   // C1 pre-negated -> already -S·x
            sG[v * 16 + 10 + f] = g12.y;
        }
        __syncthreads();
        // step2: 7 pk_fma + scalar tail; write XOR-swizzled sP
        #pragma unroll 2
        for (int j = 0; j < 16; ++j) {
            if (j < nv) {
                int v = qu + 4 * j;
                const f32x2* g2 = reinterpret_cast<const f32x2*>(sG + v * 16);
                f32x2 acc = g2[0] * th2[0];
                acc += g2[1] * th2[1]; acc += g2[2] * th2[2]; acc += g2[3] * th2[3];
                acc += g2[4] * th2[4]; acc += g2[5] * th2[5]; acc += g2[6] * th2[6];
                float s = acc.x + acc.y + sG[v * 16 + 14] * th14;
                sP[v * 64 + (o ^ (v & 31))] = fmaxf(s, 0.f);
            }
        }
        __syncthreads();
        // step3: lane=v; per c: 1 LDS read + uniform twt loads + 8 pk_fma
        const float* twtp = twt + t * 4096;
        #pragma unroll 2
        for (int c = 0; c < 64; ++c) {
            float g = sP[vlane * 64 + (c ^ swz)];
            f32x2 gg = {g, g};
            const f32x2* wr = reinterpret_cast<const f32x2*>(twtp + c * 64 + qo);
            #pragma unroll
            for (int m = 0; m < 8; ++m) accv[m] += gg * wr[m];
        }
    }

    // ---- z-phase: lane=v computes z[v][qo+m], stage in sP ----
    __syncthreads();
    if (vlane < 62) {
        float x5[5];
        #pragma unroll
        for (int f = 0; f < 5; ++f) x5[f] = sx[vlane * 5 + f];   // x[:,0]
        #pragma unroll
        for (int m = 0; m < 16; ++m) {
            int oo = qo + m;
            float am = (m & 1) ? accv[m >> 1].y : accv[m >> 1].x;
            float r = rb[oo];
            #pragma unroll
            for (int f = 0; f < 5; ++f) r += x5[f] * rw[oo * 5 + f];
            float z = r + (am + tb[oo]) * INV_SQRT15;
            sP[vlane * 64 + (oo ^ swz)] = fmaxf(z, 0.f);
        }
    }
    __syncthreads();

    // ---- epilogue: lane=o, LayerNorm over o ----
    const float gam = gamma_[o], bet = beta_[o];
    #pragma unroll
    for (int j = 0; j < 16; ++j) {
        if (j < nv) {
            int v = qu + 4 * j;
            float z = sP[v * 64 + (o ^ (v & 31))];
            float s1 = z, s2 = z * z;
            #pragma unroll
            for (int m = 1; m < 64; m <<= 1) {
                s1 += __shfl_xor(s1, m, 64);
                s2 += __shfl_xor(s2, m, 64);
            }
            float mean = s1 * 0.015625f;
            float var  = s2 * 0.015625f - mean * mean;
            float ov   = (z - mean) * rsqrtf(var + 1e-5f) * gam + bet;
            out[XR_OFF + (size_t)b * 3968 + v * 64 + o] = ov;
        }
    }
}

extern "C" void kernel_launch(void* const* d_in, const int* in_sizes, int n_in,
                              void* d_out, int out_size, void* d_ws, size_t ws_size,
                              hipStream_t stream) {
    const float* x   = (const float*)d_in[0];
    const float* U1  = (const float*)d_in[1];
    const float* U2  = (const float*)d_in[2];
    const float* U3  = (const float*)d_in[3];
    const float* be  = (const float*)d_in[4];
    const float* Ve  = (const float*)d_in[5];
    const float* W1  = (const float*)d_in[6];
    const float* W2  = (const float*)d_in[7];
    const float* W3  = (const float*)d_in[8];
    const float* bs  = (const float*)d_in[9];
    const float* Vs  = (const float*)d_in[10];
    const float* a   = (const float*)d_in[11];
    const float* Th  = (const float*)d_in[12];
    const float* tw  = (const float*)d_in[13];
    const float* tb  = (const float*)d_in[14];
    const float* rw  = (const float*)d_in[15];
    const float* rb  = (const float*)d_in[16];
    const float* gm  = (const float*)d_in[17];
    const float* bt  = (const float*)d_in[18];
    float* out = (float*)d_out;
    float* twt = (float*)d_ws;  // 12288 floats

    prep_kernel<<<48, 256, 0, stream>>>(tw, twt, out);
    stgcn_kernel<<<2048, 256, 0, stream>>>(x, U1, U2, U3, be, Ve, W1, W2, W3,
                                           bs, Vs, a, Th, twt, tb, rw, rb, gm, bt, out);
}